// Round 8
// baseline (505.780 us; speedup 1.0000x reference)
//
#include <hip/hip_runtime.h>
#include <hip/hip_bf16.h>

#define D 128
#define NNODES 16384
#define NEDGES 262144
#define NBATCH 2
#define TE 64
#define EGRID 2048
#define NT 4

typedef __attribute__((ext_vector_type(8))) short bf16x8;
typedef __attribute__((ext_vector_type(4))) float f32x4;

__device__ __forceinline__ unsigned short f2bf(float f) {
    unsigned int u = __float_as_uint(f);
    unsigned int r = (u + 0x7fffu + ((u >> 16) & 1u)) >> 16;
    return (unsigned short)r;
}

__device__ __forceinline__ unsigned int pk2bf(float lo, float hi) {
    return (unsigned int)f2bf(lo) | ((unsigned int)f2bf(hi) << 16);
}

__device__ __forceinline__ float bf2f(unsigned short u) {
    return __uint_as_float(((unsigned int)u) << 16);
}

// --------------------------------------------------------------- weight prep
// wbf layout (ushort offsets):
//   w1ef @ 0     : We1 E-part (rows 256..383) in MFMA B-frag order, ks<4
//   w2f  @ 16384 : We2 frag order, ks<4
//   wp   @ 32768 : [W1s|W1r] as [j][k]: wp[j*128+k] = We1[(j<128?k:128+k)][j&127]
//   wn1t @ 65536 : Wn1^T [n][k] k<256
//   wn2t @ 98304 : Wn2^T [n][k] k<128
__global__ __launch_bounds__(256)
void prep_weights(const float* __restrict__ We1, const float* __restrict__ We2,
                  const float* __restrict__ Wn1, const float* __restrict__ Wn2,
                  unsigned short* __restrict__ w)
{
    int id = blockIdx.x * 256 + threadIdx.x;   // 114688 total
    if (id < 16384) {
        int e = id & 7, l = (id >> 3) & 63, nblk = (id >> 9) & 7, ks = id >> 12;
        int k = 256 + ks * 32 + ((l >> 4) & 3) * 8 + e;
        int col = nblk * 16 + (l & 15);
        w[id] = f2bf(We1[k * 128 + col]);
    } else if (id < 32768) {
        int i2 = id - 16384;
        int e = i2 & 7, l = (i2 >> 3) & 63, nblk = (i2 >> 9) & 7, ks = i2 >> 12;
        int k = ks * 32 + ((l >> 4) & 3) * 8 + e;
        int col = nblk * 16 + (l & 15);
        w[id] = f2bf(We2[k * 128 + col]);
    } else if (id < 65536) {
        int i3 = id - 32768;
        int j = i3 >> 7, k = i3 & 127;
        int row = (j < 128) ? k : (128 + k);
        w[id] = f2bf(We1[row * 128 + (j & 127)]);
    } else if (id < 98304) {
        int i4 = id - 65536;
        int n = i4 >> 8, k = i4 & 255;
        w[id] = f2bf(Wn1[k * 128 + n]);
    } else {
        int i5 = id - 98304;
        int n = i5 >> 7, k = i5 & 127;
        w[id] = f2bf(Wn2[k * 128 + n]);
    }
}

// ------------------------------------------------------------ partial kernel
// P[r][j] = sum_k V[r][k] * wp[j][k],  r < 32768, j < 256.
__global__ __launch_bounds__(256)
void partial_kernel(const float* __restrict__ V, const unsigned short* __restrict__ wp,
                    unsigned short* __restrict__ P)
{
    __shared__ unsigned short smem[64 * 136];
    const int t = threadIdx.x, lane = t & 63, wave = t >> 6;
    const int l15 = lane & 15, l4 = lane >> 4;
    const long long r0 = (long long)blockIdx.x * 64;

    for (int i = t; i < 64 * 32; i += 256) {
        int c4 = i & 31, r = i >> 5;
        float4 v = *(const float4*)(V + (r0 + r) * 128 + c4 * 4);
        uint2 p; p.x = pk2bf(v.x, v.y); p.y = pk2bf(v.z, v.w);
        *(uint2*)(&smem[r * 136 + c4 * 4]) = p;
    }
    __syncthreads();

    const int j0 = wave * 64;
    f32x4 acc[4][4] = {};
    const unsigned short* bb0 = wp + (j0 + l15) * 128 + l4 * 8;
    #pragma unroll
    for (int ks = 0; ks < 4; ++ks) {
        bf16x8 bb[4];
        #pragma unroll
        for (int n = 0; n < 4; ++n)
            bb[n] = *(const bf16x8*)(bb0 + n * 16 * 128 + ks * 32);
        #pragma unroll
        for (int mq = 0; mq < 4; ++mq) {
            bf16x8 a = *(const bf16x8*)(&smem[(mq * 16 + l15) * 136 + l4 * 8 + ks * 32]);
            #pragma unroll
            for (int n = 0; n < 4; ++n)
                acc[mq][n] = __builtin_amdgcn_mfma_f32_16x16x32_bf16(a, bb[n], acc[mq][n], 0, 0, 0);
        }
    }
    #pragma unroll
    for (int mq = 0; mq < 4; ++mq) {
        #pragma unroll
        for (int n = 0; n < 4; ++n) {
            #pragma unroll
            for (int i = 0; i < 4; ++i) {
                int row = mq * 16 + l4 * 4 + i;
                int col = j0 + n * 16 + l15;
                P[(r0 + row) * 256 + col] = f2bf(acc[mq][n][i]);
            }
        }
    }
}

// ---------------------------------------------------------------- edge kernel
// Pipelined persistent blocks: NT=4 tiles/block, next tile's E rows + edge
// indices prefetched global->reg at iteration top (latency hides under
// MFMA1 + P-gather + MFMA2), committed reg->LDS after last consumer of the
// old buffer. 2 barriers/tile. LDS 35.3KB -> 4 blocks/CU.
__global__ __launch_bounds__(256)
void edge_kernel(const float* __restrict__ E, const int* __restrict__ edges,
                 const unsigned short* __restrict__ P,
                 const unsigned short* __restrict__ w1ef, const float* __restrict__ be1,
                 const unsigned short* __restrict__ w2f, const float* __restrict__ be2,
                 float* __restrict__ m0sum, float* __restrict__ m1sum,
                 float* __restrict__ c0, float* __restrict__ c1)
{
    __shared__ unsigned short Ebuf[TE * 136];
    __shared__ unsigned short Hbuf[TE * 136];
    __shared__ int eidx[TE][2];

    const int t    = threadIdx.x;
    const int lane = t & 63;
    const int wave = t >> 6;
    const int wr   = wave >> 1;
    const int wc   = wave & 1;
    const int l15  = lane & 15;
    const int l4   = lane >> 4;
    const int sc4  = t & 31;          // staging float4-col (coalesced)
    const int se0  = t >> 5;          // staging row base

    float4 pre[8];
    int preidx = 0;

    long long tile = blockIdx.x;

    // -------- prologue: stage tile 0 --------
    {
        const long long ef0 = tile * TE;
        #pragma unroll
        for (int j = 0; j < 8; ++j)
            pre[j] = *(const float4*)(E + (ef0 + se0 + j * 8) * D + sc4 * 4);
        if (t < TE * 2) preidx = edges[(ef0 + (t >> 1)) * 2 + (t & 1)];
        #pragma unroll
        for (int j = 0; j < 8; ++j) {
            uint2 p; p.x = pk2bf(pre[j].x, pre[j].y); p.y = pk2bf(pre[j].z, pre[j].w);
            *(uint2*)(&Ebuf[(se0 + j * 8) * 136 + sc4 * 4]) = p;
        }
        if (t < TE * 2) eidx[t >> 1][t & 1] = preidx;
    }
    __syncthreads();   // barrier A

    for (int it = 0; it < NT; ++it) {
        const bool have_next = (it + 1 < NT);
        const long long tile_next = tile + EGRID;

        // issue next tile's global loads (consumed after MFMA2)
        if (have_next) {
            const long long ef1 = tile_next * TE;
            #pragma unroll
            for (int j = 0; j < 8; ++j)
                pre[j] = *(const float4*)(E + (ef1 + se0 + j * 8) * D + sc4 * 4);
            if (t < TE * 2) preidx = edges[(ef1 + (t >> 1)) * 2 + (t & 1)];
        }

        const long long eflat0 = tile * TE;
        const int b = (int)(eflat0 / NEDGES);
        const long long nb0 = (long long)b * NNODES;

        // per-tile degree counts (eidx stable between barrier A and barrier B)
        if (t < TE)          atomicAdd(&c0[nb0 + eidx[t][0]], 1.f);
        else if (t < 2 * TE) atomicAdd(&c1[nb0 + eidx[t - TE][1]], 1.f);

        // ---- layer 1 (E part): [64x128] @ [128x128] ----
        f32x4 acc[2][4] = {};
        {
            const unsigned short* arow = &Ebuf[(wr * 32 + l15) * 136 + l4 * 8];
            #pragma unroll
            for (int ks = 0; ks < 4; ++ks) {
                bf16x8 a0 = *(const bf16x8*)(arow + ks * 32);
                bf16x8 a1 = *(const bf16x8*)(arow + 16 * 136 + ks * 32);
                #pragma unroll
                for (int n = 0; n < 4; ++n) {
                    bf16x8 bb = *(const bf16x8*)(w1ef + (((ks * 8 + wc * 4 + n) * 64 + lane) << 3));
                    acc[0][n] = __builtin_amdgcn_mfma_f32_16x16x32_bf16(a0, bb, acc[0][n], 0, 0, 0);
                    acc[1][n] = __builtin_amdgcn_mfma_f32_16x16x32_bf16(a1, bb, acc[1][n], 0, 0, 0);
                }
            }
        }

        // hoist scatter/gather node indices to registers (last eidx LDS reads)
        int nd0[2][4], nd1[2][4];
        #pragma unroll
        for (int m = 0; m < 2; ++m) {
            #pragma unroll
            for (int i = 0; i < 4; ++i) {
                int row = wr * 32 + m * 16 + l4 * 4 + i;
                nd0[m][i] = eidx[row][0];
                nd1[m][i] = eidx[row][1];
            }
        }

        // epilogue: + P[snd] + P[rcv] + bias, silu -> Hbuf
        #pragma unroll
        for (int n = 0; n < 4; ++n) {
            int col = wc * 64 + n * 16 + l15;
            float bias = be1[col];
            #pragma unroll
            for (int m = 0; m < 2; ++m) {
                #pragma unroll
                for (int i = 0; i < 4; ++i) {
                    int row = wr * 32 + m * 16 + l4 * 4 + i;
                    float a = acc[m][n][i] + bias
                            + bf2f(P[(nb0 + nd0[m][i]) * 256 + col])
                            + bf2f(P[(nb0 + nd1[m][i]) * 256 + 128 + col]);
                    Hbuf[row * 136 + col] = f2bf(a / (1.f + __expf(-a)));
                }
            }
        }
        __syncthreads();   // barrier B: Hbuf ready; Ebuf/eidx consumers done

        // ---- layer 2: [64x128] @ [128x128] ----
        f32x4 acc2[2][4] = {};
        {
            const unsigned short* hrow = &Hbuf[(wr * 32 + l15) * 136 + l4 * 8];
            #pragma unroll
            for (int ks = 0; ks < 4; ++ks) {
                bf16x8 a0 = *(const bf16x8*)(hrow + ks * 32);
                bf16x8 a1 = *(const bf16x8*)(hrow + 16 * 136 + ks * 32);
                #pragma unroll
                for (int n = 0; n < 4; ++n) {
                    bf16x8 bb = *(const bf16x8*)(w2f + (((ks * 8 + wc * 4 + n) * 64 + lane) << 3));
                    acc2[0][n] = __builtin_amdgcn_mfma_f32_16x16x32_bf16(a0, bb, acc2[0][n], 0, 0, 0);
                    acc2[1][n] = __builtin_amdgcn_mfma_f32_16x16x32_bf16(a1, bb, acc2[1][n], 0, 0, 0);
                }
            }
        }

        // scatter (node indices from registers; 16-lane feature-coalesced)
        {
            float* dst_arr = wc ? m1sum : m0sum;
            #pragma unroll
            for (int n = 0; n < 4; ++n) {
                int colh = n * 16 + l15;
                float bias = be2[wc * 64 + colh];
                #pragma unroll
                for (int m = 0; m < 2; ++m) {
                    #pragma unroll
                    for (int i = 0; i < 4; ++i) {
                        int node = wc ? nd1[m][i] : nd0[m][i];
                        atomicAdd(dst_arr + (nb0 + node) * 64 + colh,
                                  acc2[m][n][i] + bias);
                    }
                }
            }
        }

        // commit prefetched tile to LDS (safe: all Ebuf/eidx readers passed barrier B)
        if (have_next) {
            #pragma unroll
            for (int j = 0; j < 8; ++j) {
                uint2 p; p.x = pk2bf(pre[j].x, pre[j].y); p.y = pk2bf(pre[j].z, pre[j].w);
                *(uint2*)(&Ebuf[(se0 + j * 8) * 136 + sc4 * 4]) = p;
            }
            if (t < TE * 2) eidx[t >> 1][t & 1] = preidx;
        }
        __syncthreads();   // barrier A for next iteration
        tile = tile_next;
    }
}

// ---------------------------------------------------------------- node kernel
__global__ __launch_bounds__(256)
void node_kernel(const float* __restrict__ V,
                 const float* __restrict__ m0sum, const float* __restrict__ m1sum,
                 const float* __restrict__ c0, const float* __restrict__ c1,
                 const unsigned short* __restrict__ wn1t, const float* __restrict__ bn1,
                 const unsigned short* __restrict__ wn2t, const float* __restrict__ bn2,
                 float* __restrict__ node_emb)
{
    __shared__ unsigned short smem[TE * 264];   // A [64][264]; reused as H [64][136]

    const int t    = threadIdx.x;
    const int lane = t & 63;
    const int wave = t >> 6;
    const int wr   = wave >> 1;
    const int wc   = wave & 1;
    const int l15  = lane & 15;
    const int l4   = lane >> 4;

    const long long nflat0 = (long long)blockIdx.x * TE;

    for (int i = t; i < TE * 64; i += 256) {
        int c4 = i & 63;
        int n  = i >> 6;
        long long node = nflat0 + n;
        float4 v; int off;
        if (c4 < 32) {
            v = *(const float4*)(V + node * 128 + c4 * 4);
            off = c4 * 4;
        } else if (c4 < 48) {
            v = *(const float4*)(m0sum + node * 64 + (c4 - 32) * 4);
            float inv = 1.f / fmaxf(c0[node], 1.f);
            v.x *= inv; v.y *= inv; v.z *= inv; v.w *= inv;
            off = 128 + (c4 - 32) * 4;
        } else {
            v = *(const float4*)(m1sum + node * 64 + (c4 - 48) * 4);
            float inv = 1.f / fmaxf(c1[node], 1.f);
            v.x *= inv; v.y *= inv; v.z *= inv; v.w *= inv;
            off = 192 + (c4 - 48) * 4;
        }
        uint2 p;
        p.x = pk2bf(v.x, v.y);
        p.y = pk2bf(v.z, v.w);
        *(uint2*)(&smem[n * 264 + c4 * 4]) = p;
    }
    __syncthreads();

    f32x4 acc[2][4] = {};
    {
        const unsigned short* arow = &smem[(wr * 32 + l15) * 264 + l4 * 8];
        const unsigned short* bb0  = wn1t + (wc * 64 + l15) * 256 + l4 * 8;
        for (int ks = 0; ks < 8; ++ks) {
            bf16x8 a0 = *(const bf16x8*)(arow + ks * 32);
            bf16x8 a1 = *(const bf16x8*)(arow + 16 * 264 + ks * 32);
            #pragma unroll
            for (int n = 0; n < 4; ++n) {
                bf16x8 bb = *(const bf16x8*)(bb0 + n * 16 * 256 + ks * 32);
                acc[0][n] = __builtin_amdgcn_mfma_f32_16x16x32_bf16(a0, bb, acc[0][n], 0, 0, 0);
                acc[1][n] = __builtin_amdgcn_mfma_f32_16x16x32_bf16(a1, bb, acc[1][n], 0, 0, 0);
            }
        }
    }
    __syncthreads();

    #pragma unroll
    for (int n = 0; n < 4; ++n) {
        int col = wc * 64 + n * 16 + l15;
        float bias = bn1[col];
        #pragma unroll
        for (int m = 0; m < 2; ++m) {
            #pragma unroll
            for (int i = 0; i < 4; ++i) {
                int row = wr * 32 + m * 16 + l4 * 4 + i;
                float a = acc[m][n][i] + bias;
                smem[row * 136 + col] = f2bf(a / (1.f + __expf(-a)));
            }
        }
    }
    __syncthreads();

    f32x4 acc2[2][4] = {};
    {
        const unsigned short* hrow = &smem[(wr * 32 + l15) * 136 + l4 * 8];
        const unsigned short* bb0  = wn2t + (wc * 64 + l15) * 128 + l4 * 8;
        #pragma unroll
        for (int ks = 0; ks < 4; ++ks) {
            bf16x8 a0 = *(const bf16x8*)(hrow + ks * 32);
            bf16x8 a1 = *(const bf16x8*)(hrow + 16 * 136 + ks * 32);
            #pragma unroll
            for (int n = 0; n < 4; ++n) {
                bf16x8 bb = *(const bf16x8*)(bb0 + n * 16 * 128 + ks * 32);
                acc2[0][n] = __builtin_amdgcn_mfma_f32_16x16x32_bf16(a0, bb, acc2[0][n], 0, 0, 0);
                acc2[1][n] = __builtin_amdgcn_mfma_f32_16x16x32_bf16(a1, bb, acc2[1][n], 0, 0, 0);
            }
        }
    }

    #pragma unroll
    for (int n = 0; n < 4; ++n) {
        int col = wc * 64 + n * 16 + l15;
        float bias = bn2[col];
        #pragma unroll
        for (int m = 0; m < 2; ++m) {
            #pragma unroll
            for (int i = 0; i < 4; ++i) {
                long long row = nflat0 + wr * 32 + m * 16 + l4 * 4 + i;
                node_emb[row * 128 + col] = acc2[m][n][i] + bias;
            }
        }
    }
}

// ------------------------------------------------------------ attention kernel
__global__ __launch_bounds__(256)
void attn_kernel(const float* __restrict__ blocks, const float* __restrict__ node_emb,
                 const float* __restrict__ w_attn, const float* __restrict__ rms_w,
                 float* __restrict__ out)
{
    const int t    = threadIdx.x;
    const int wave = t >> 6;
    const int lane = t & 63;
    const long long node = (long long)blockIdx.x * 4 + wave;
    const int d0 = lane * 2;

    float2 wa = *(const float2*)(w_attn + d0);
    float2 rw = *(const float2*)(rms_w + d0);

    float xs[5][2];
    float lg[5];
    #pragma unroll
    for (int s = 0; s < 5; ++s) {
        const float* src = (s < 4)
            ? (blocks + ((long long)s * NBATCH * NNODES + node) * 128)
            : (node_emb + node * 128);
        float2 x = *(const float2*)(src + d0);
        xs[s][0] = x.x; xs[s][1] = x.y;
        float ss = x.x * x.x + x.y * x.y;
        float wv = wa.x * rw.x * x.x + wa.y * rw.y * x.y;
        #pragma unroll
        for (int m = 1; m < 64; m <<= 1) {
            ss += __shfl_xor(ss, m);
            wv += __shfl_xor(wv, m);
        }
        lg[s] = wv * rsqrtf(ss * (1.f / 128.f) + 1e-6f);
    }

    float mx = lg[0];
    #pragma unroll
    for (int s = 1; s < 5; ++s) mx = fmaxf(mx, lg[s]);
    float ex[5], sum = 0.f;
    #pragma unroll
    for (int s = 0; s < 5; ++s) { ex[s] = __expf(lg[s] - mx); sum += ex[s]; }
    float inv = 1.f / sum;

    float h0 = 0.f, h1 = 0.f;
    #pragma unroll
    for (int s = 0; s < 5; ++s) {
        float a = ex[s] * inv;
        h0 = fmaf(a, xs[s][0], h0);
        h1 = fmaf(a, xs[s][1], h1);
    }
    *(float2*)(out + node * 128 + d0) = make_float2(h0, h1);
}

// ------------------------------------------------------------------- launcher
extern "C" void kernel_launch(void* const* d_in, const int* in_sizes, int n_in,
                              void* d_out, int out_size, void* d_ws, size_t ws_size,
                              hipStream_t stream)
{
    const float* V      = (const float*)d_in[0];
    const float* E      = (const float*)d_in[1];
    const float* blocks = (const float*)d_in[2];
    const float* We1    = (const float*)d_in[3];
    const float* be1    = (const float*)d_in[4];
    const float* We2    = (const float*)d_in[5];
    const float* be2    = (const float*)d_in[6];
    const float* Wn1    = (const float*)d_in[7];
    const float* bn1    = (const float*)d_in[8];
    const float* Wn2    = (const float*)d_in[9];
    const float* bn2    = (const float*)d_in[10];
    const float* w_attn = (const float*)d_in[11];
    const float* rms_w  = (const float*)d_in[12];
    const int*   edges  = (const int*)d_in[13];
    float* out = (float*)d_out;

    float* ws = (float*)d_ws;
    float* m0sum    = ws;                         // BS*N*64
    float* m1sum    = m0sum + 2097152;
    float* c0       = m1sum + 2097152;
    float* c1       = c0 + 32768;
    float* node_emb = c1 + 32768;                 // BS*N*128
    unsigned short* wbf = (unsigned short*)(node_emb + 4194304);  // 114688 bf16
    unsigned short* w1ef = wbf;            // 16384 (frag-ordered We1 E-part)
    unsigned short* w2f  = wbf + 16384;    // 16384 (frag-ordered We2)
    unsigned short* wp   = wbf + 32768;    // 32768 ([W1s|W1r] transposed)
    unsigned short* wn1t = wbf + 65536;    // 32768
    unsigned short* wn2t = wbf + 98304;    // 16384
    unsigned short* P    = wbf + 114688;   // 32768*256 bf16 partials (16.8MB)

    (void)hipMemsetAsync(d_ws, 0, (size_t)(2097152 * 2 + 32768 * 2) * sizeof(float), stream);

    prep_weights<<<448, 256, 0, stream>>>(We1, We2, Wn1, Wn2, wbf);

    partial_kernel<<<(NBATCH * NNODES) / 64, 256, 0, stream>>>(V, wp, P);

    edge_kernel<<<EGRID, 256, 0, stream>>>(
        E, edges, P, w1ef, be1, w2f, be2, m0sum, m1sum, c0, c1);

    node_kernel<<<(NBATCH * NNODES) / TE, 256, 0, stream>>>(
        V, m0sum, m1sum, c0, c1, wn1t, bn1, wn2t, bn2, node_emb);

    attn_kernel<<<(NBATCH * NNODES) / 4, 256, 0, stream>>>(
        blocks, node_emb, w_attn, rms_w, out);
}

// Round 9
// 378.503 us; speedup vs baseline: 1.3363x; 1.3363x over previous
//
#include <hip/hip_runtime.h>
#include <hip/hip_bf16.h>

#define D 128
#define NNODES 16384
#define NEDGES 262144
#define NBATCH 2
#define TE 64

typedef __attribute__((ext_vector_type(8))) short bf16x8;
typedef __attribute__((ext_vector_type(4))) float f32x4;

__device__ __forceinline__ unsigned short f2bf(float f) {
    unsigned int u = __float_as_uint(f);
    unsigned int r = (u + 0x7fffu + ((u >> 16) & 1u)) >> 16;
    return (unsigned short)r;
}

__device__ __forceinline__ unsigned int pk2bf(float lo, float hi) {
    return (unsigned int)f2bf(lo) | ((unsigned int)f2bf(hi) << 16);
}

__device__ __forceinline__ float bf2f(unsigned short u) {
    return __uint_as_float(((unsigned int)u) << 16);
}

__device__ __forceinline__ bf16x8 pack8(f32x4 a, f32x4 b) {
    unsigned int w0 = pk2bf(a[0], a[1]);
    unsigned int w1 = pk2bf(a[2], a[3]);
    unsigned int w2 = pk2bf(b[0], b[1]);
    unsigned int w3 = pk2bf(b[2], b[3]);
    typedef __attribute__((ext_vector_type(4))) unsigned int u32x4;
    u32x4 u; u.x = w0; u.y = w1; u.z = w2; u.w = w3;
    return __builtin_bit_cast(bf16x8, u);
}

// --------------------------------------------------------------- weight prep
// wbf layout (ushort offsets):
//   w1ef @ 0     : We1 E-part (rows 256..383) in MFMA B-frag order, ks<4
//   w2f  @ 16384 : We2 frag order, ks<4
//   wp   @ 32768 : [W1s|W1r] as [j][k]: wp[j*128+k] = We1[(j<128?k:128+k)][j&127]
//   wn1t @ 65536 : Wn1^T [n][k] k<256
//   wn2t @ 98304 : Wn2^T [n][k] k<128
__global__ __launch_bounds__(256)
void prep_weights(const float* __restrict__ We1, const float* __restrict__ We2,
                  const float* __restrict__ Wn1, const float* __restrict__ Wn2,
                  unsigned short* __restrict__ w)
{
    int id = blockIdx.x * 256 + threadIdx.x;   // 114688 total
    if (id < 16384) {
        int e = id & 7, l = (id >> 3) & 63, nblk = (id >> 9) & 7, ks = id >> 12;
        int k = 256 + ks * 32 + ((l >> 4) & 3) * 8 + e;
        int col = nblk * 16 + (l & 15);
        w[id] = f2bf(We1[k * 128 + col]);
    } else if (id < 32768) {
        int i2 = id - 16384;
        int e = i2 & 7, l = (i2 >> 3) & 63, nblk = (i2 >> 9) & 7, ks = i2 >> 12;
        int k = ks * 32 + ((l >> 4) & 3) * 8 + e;
        int col = nblk * 16 + (l & 15);
        w[id] = f2bf(We2[k * 128 + col]);
    } else if (id < 65536) {
        int i3 = id - 32768;
        int j = i3 >> 7, k = i3 & 127;
        int row = (j < 128) ? k : (128 + k);
        w[id] = f2bf(We1[row * 128 + (j & 127)]);
    } else if (id < 98304) {
        int i4 = id - 65536;
        int n = i4 >> 8, k = i4 & 255;
        w[id] = f2bf(Wn1[k * 128 + n]);
    } else {
        int i5 = id - 98304;
        int n = i5 >> 7, k = i5 & 127;
        w[id] = f2bf(Wn2[k * 128 + n]);
    }
}

// ------------------------------------------------------------ partial kernel
// P[r][j] = sum_k V[r][k] * wp[j][k],  r < 32768, j < 256.
__global__ __launch_bounds__(256)
void partial_kernel(const float* __restrict__ V, const unsigned short* __restrict__ wp,
                    unsigned short* __restrict__ P)
{
    __shared__ unsigned short smem[64 * 136];
    const int t = threadIdx.x, lane = t & 63, wave = t >> 6;
    const int l15 = lane & 15, l4 = lane >> 4;
    const long long r0 = (long long)blockIdx.x * 64;

    for (int i = t; i < 64 * 32; i += 256) {
        int c4 = i & 31, r = i >> 5;
        float4 v = *(const float4*)(V + (r0 + r) * 128 + c4 * 4);
        uint2 p; p.x = pk2bf(v.x, v.y); p.y = pk2bf(v.z, v.w);
        *(uint2*)(&smem[r * 136 + c4 * 4]) = p;
    }
    __syncthreads();

    const int j0 = wave * 64;
    f32x4 acc[4][4] = {};
    const unsigned short* bb0 = wp + (j0 + l15) * 128 + l4 * 8;
    #pragma unroll
    for (int ks = 0; ks < 4; ++ks) {
        bf16x8 bb[4];
        #pragma unroll
        for (int n = 0; n < 4; ++n)
            bb[n] = *(const bf16x8*)(bb0 + n * 16 * 128 + ks * 32);
        #pragma unroll
        for (int mq = 0; mq < 4; ++mq) {
            bf16x8 a = *(const bf16x8*)(&smem[(mq * 16 + l15) * 136 + l4 * 8 + ks * 32]);
            #pragma unroll
            for (int n = 0; n < 4; ++n)
                acc[mq][n] = __builtin_amdgcn_mfma_f32_16x16x32_bf16(a, bb[n], acc[mq][n], 0, 0, 0);
        }
    }
    #pragma unroll
    for (int mq = 0; mq < 4; ++mq) {
        #pragma unroll
        for (int n = 0; n < 4; ++n) {
            #pragma unroll
            for (int i = 0; i < 4; ++i) {
                int row = mq * 16 + l4 * 4 + i;
                int col = j0 + n * 16 + l15;
                P[(r0 + row) * 256 + col] = f2bf(acc[mq][n][i]);
            }
        }
    }
}

// ---------------------------------------------------------------- edge kernel
// Single-barrier version: A-fragments of E loaded DIRECTLY global->reg
// (lane l15 reads 8 consecutive f32 of edge row wr*32+l15 -> 2x dwordx4 +
// cvt_pk). No E LDS tile, no eidx LDS (per-lane int2 loads, L1-hot).
// Only LDS use is the H handoff (17.4KB -> ~9 blocks/CU).
__global__ __launch_bounds__(256)
void edge_kernel(const float* __restrict__ E, const int* __restrict__ edges,
                 const unsigned short* __restrict__ P,
                 const unsigned short* __restrict__ w1ef, const float* __restrict__ be1,
                 const unsigned short* __restrict__ w2f, const float* __restrict__ be2,
                 float* __restrict__ m0sum, float* __restrict__ m1sum,
                 float* __restrict__ c0, float* __restrict__ c1)
{
    __shared__ unsigned short Hbuf[TE * 136];

    const int t    = threadIdx.x;
    const int lane = t & 63;
    const int wave = t >> 6;
    const int wr   = wave >> 1;
    const int wc   = wave & 1;
    const int l15  = lane & 15;
    const int l4   = lane >> 4;

    const long long eflat0 = (long long)blockIdx.x * TE;
    const int b  = (int)(eflat0 / NEDGES);
    const long long nb0 = (long long)b * NNODES;

    // degree counts (1M atomics total, negligible)
    if (t < TE) {
        int2 e2 = *(const int2*)(edges + (eflat0 + t) * 2);
        atomicAdd(&c0[nb0 + e2.x], 1.f);
        atomicAdd(&c1[nb0 + e2.y], 1.f);
    }

    // ---- layer 1 (E part): [64x128] @ [128x128], A direct from global ----
    f32x4 acc[2][4] = {};
    {
        const float* er0 = E + (eflat0 + wr * 32 + l15) * D + l4 * 8;
        #pragma unroll
        for (int ks = 0; ks < 4; ++ks) {
            f32x4 xa0 = *(const f32x4*)(er0 + ks * 32);
            f32x4 xb0 = *(const f32x4*)(er0 + ks * 32 + 4);
            f32x4 xa1 = *(const f32x4*)(er0 + 16 * D + ks * 32);
            f32x4 xb1 = *(const f32x4*)(er0 + 16 * D + ks * 32 + 4);
            bf16x8 a0 = pack8(xa0, xb0);
            bf16x8 a1 = pack8(xa1, xb1);
            #pragma unroll
            for (int n = 0; n < 4; ++n) {
                bf16x8 bb = *(const bf16x8*)(w1ef + (((ks * 8 + wc * 4 + n) * 64 + lane) << 3));
                acc[0][n] = __builtin_amdgcn_mfma_f32_16x16x32_bf16(a0, bb, acc[0][n], 0, 0, 0);
                acc[1][n] = __builtin_amdgcn_mfma_f32_16x16x32_bf16(a1, bb, acc[1][n], 0, 0, 0);
            }
        }
    }

    // node indices for epilogue/scatter: per-lane int2 loads (512B block, L1)
    int nd0[2][4], nd1[2][4];
    #pragma unroll
    for (int m = 0; m < 2; ++m) {
        #pragma unroll
        for (int i = 0; i < 4; ++i) {
            int row = wr * 32 + m * 16 + l4 * 4 + i;
            int2 e2 = *(const int2*)(edges + (eflat0 + row) * 2);
            nd0[m][i] = e2.x;
            nd1[m][i] = e2.y;
        }
    }

    // epilogue: + P[snd] + P[rcv] + bias, silu -> Hbuf
    #pragma unroll
    for (int n = 0; n < 4; ++n) {
        int col = wc * 64 + n * 16 + l15;
        float bias = be1[col];
        #pragma unroll
        for (int m = 0; m < 2; ++m) {
            #pragma unroll
            for (int i = 0; i < 4; ++i) {
                int row = wr * 32 + m * 16 + l4 * 4 + i;
                float a = acc[m][n][i] + bias
                        + bf2f(P[(nb0 + nd0[m][i]) * 256 + col])
                        + bf2f(P[(nb0 + nd1[m][i]) * 256 + 128 + col]);
                Hbuf[row * 136 + col] = f2bf(a / (1.f + __expf(-a)));
            }
        }
    }
    __syncthreads();   // single barrier: H handoff

    // ---- layer 2: [64x128] @ [128x128] ----
    f32x4 acc2[2][4] = {};
    {
        const unsigned short* hrow = &Hbuf[(wr * 32 + l15) * 136 + l4 * 8];
        #pragma unroll
        for (int ks = 0; ks < 4; ++ks) {
            bf16x8 a0 = *(const bf16x8*)(hrow + ks * 32);
            bf16x8 a1 = *(const bf16x8*)(hrow + 16 * 136 + ks * 32);
            #pragma unroll
            for (int n = 0; n < 4; ++n) {
                bf16x8 bb = *(const bf16x8*)(w2f + (((ks * 8 + wc * 4 + n) * 64 + lane) << 3));
                acc2[0][n] = __builtin_amdgcn_mfma_f32_16x16x32_bf16(a0, bb, acc2[0][n], 0, 0, 0);
                acc2[1][n] = __builtin_amdgcn_mfma_f32_16x16x32_bf16(a1, bb, acc2[1][n], 0, 0, 0);
            }
        }
    }

    // scatter: 16 consecutive lanes = 16 consecutive feats of one node
    {
        float* dst_arr = wc ? m1sum : m0sum;
        #pragma unroll
        for (int n = 0; n < 4; ++n) {
            int colh = n * 16 + l15;
            float bias = be2[wc * 64 + colh];
            #pragma unroll
            for (int m = 0; m < 2; ++m) {
                #pragma unroll
                for (int i = 0; i < 4; ++i) {
                    int node = wc ? nd1[m][i] : nd0[m][i];
                    atomicAdd(dst_arr + (nb0 + node) * 64 + colh,
                              acc2[m][n][i] + bias);
                }
            }
        }
    }
}

// ---------------------------------------------------------------- node kernel
__global__ __launch_bounds__(256)
void node_kernel(const float* __restrict__ V,
                 const float* __restrict__ m0sum, const float* __restrict__ m1sum,
                 const float* __restrict__ c0, const float* __restrict__ c1,
                 const unsigned short* __restrict__ wn1t, const float* __restrict__ bn1,
                 const unsigned short* __restrict__ wn2t, const float* __restrict__ bn2,
                 float* __restrict__ node_emb)
{
    __shared__ unsigned short smem[TE * 264];   // A [64][264]; reused as H [64][136]

    const int t    = threadIdx.x;
    const int lane = t & 63;
    const int wave = t >> 6;
    const int wr   = wave >> 1;
    const int wc   = wave & 1;
    const int l15  = lane & 15;
    const int l4   = lane >> 4;

    const long long nflat0 = (long long)blockIdx.x * TE;

    for (int i = t; i < TE * 64; i += 256) {
        int c4 = i & 63;
        int n  = i >> 6;
        long long node = nflat0 + n;
        float4 v; int off;
        if (c4 < 32) {
            v = *(const float4*)(V + node * 128 + c4 * 4);
            off = c4 * 4;
        } else if (c4 < 48) {
            v = *(const float4*)(m0sum + node * 64 + (c4 - 32) * 4);
            float inv = 1.f / fmaxf(c0[node], 1.f);
            v.x *= inv; v.y *= inv; v.z *= inv; v.w *= inv;
            off = 128 + (c4 - 32) * 4;
        } else {
            v = *(const float4*)(m1sum + node * 64 + (c4 - 48) * 4);
            float inv = 1.f / fmaxf(c1[node], 1.f);
            v.x *= inv; v.y *= inv; v.z *= inv; v.w *= inv;
            off = 192 + (c4 - 48) * 4;
        }
        uint2 p;
        p.x = pk2bf(v.x, v.y);
        p.y = pk2bf(v.z, v.w);
        *(uint2*)(&smem[n * 264 + c4 * 4]) = p;
    }
    __syncthreads();

    f32x4 acc[2][4] = {};
    {
        const unsigned short* arow = &smem[(wr * 32 + l15) * 264 + l4 * 8];
        const unsigned short* bb0  = wn1t + (wc * 64 + l15) * 256 + l4 * 8;
        for (int ks = 0; ks < 8; ++ks) {
            bf16x8 a0 = *(const bf16x8*)(arow + ks * 32);
            bf16x8 a1 = *(const bf16x8*)(arow + 16 * 264 + ks * 32);
            #pragma unroll
            for (int n = 0; n < 4; ++n) {
                bf16x8 bb = *(const bf16x8*)(bb0 + n * 16 * 256 + ks * 32);
                acc[0][n] = __builtin_amdgcn_mfma_f32_16x16x32_bf16(a0, bb, acc[0][n], 0, 0, 0);
                acc[1][n] = __builtin_amdgcn_mfma_f32_16x16x32_bf16(a1, bb, acc[1][n], 0, 0, 0);
            }
        }
    }
    __syncthreads();

    #pragma unroll
    for (int n = 0; n < 4; ++n) {
        int col = wc * 64 + n * 16 + l15;
        float bias = bn1[col];
        #pragma unroll
        for (int m = 0; m < 2; ++m) {
            #pragma unroll
            for (int i = 0; i < 4; ++i) {
                int row = wr * 32 + m * 16 + l4 * 4 + i;
                float a = acc[m][n][i] + bias;
                smem[row * 136 + col] = f2bf(a / (1.f + __expf(-a)));
            }
        }
    }
    __syncthreads();

    f32x4 acc2[2][4] = {};
    {
        const unsigned short* hrow = &smem[(wr * 32 + l15) * 136 + l4 * 8];
        const unsigned short* bb0  = wn2t + (wc * 64 + l15) * 128 + l4 * 8;
        #pragma unroll
        for (int ks = 0; ks < 4; ++ks) {
            bf16x8 a0 = *(const bf16x8*)(hrow + ks * 32);
            bf16x8 a1 = *(const bf16x8*)(hrow + 16 * 136 + ks * 32);
            #pragma unroll
            for (int n = 0; n < 4; ++n) {
                bf16x8 bb = *(const bf16x8*)(bb0 + n * 16 * 128 + ks * 32);
                acc2[0][n] = __builtin_amdgcn_mfma_f32_16x16x32_bf16(a0, bb, acc2[0][n], 0, 0, 0);
                acc2[1][n] = __builtin_amdgcn_mfma_f32_16x16x32_bf16(a1, bb, acc2[1][n], 0, 0, 0);
            }
        }
    }

    #pragma unroll
    for (int n = 0; n < 4; ++n) {
        int col = wc * 64 + n * 16 + l15;
        float bias = bn2[col];
        #pragma unroll
        for (int m = 0; m < 2; ++m) {
            #pragma unroll
            for (int i = 0; i < 4; ++i) {
                long long row = nflat0 + wr * 32 + m * 16 + l4 * 4 + i;
                node_emb[row * 128 + col] = acc2[m][n][i] + bias;
            }
        }
    }
}

// ------------------------------------------------------------ attention kernel
__global__ __launch_bounds__(256)
void attn_kernel(const float* __restrict__ blocks, const float* __restrict__ node_emb,
                 const float* __restrict__ w_attn, const float* __restrict__ rms_w,
                 float* __restrict__ out)
{
    const int t    = threadIdx.x;
    const int wave = t >> 6;
    const int lane = t & 63;
    const long long node = (long long)blockIdx.x * 4 + wave;
    const int d0 = lane * 2;

    float2 wa = *(const float2*)(w_attn + d0);
    float2 rw = *(const float2*)(rms_w + d0);

    float xs[5][2];
    float lg[5];
    #pragma unroll
    for (int s = 0; s < 5; ++s) {
        const float* src = (s < 4)
            ? (blocks + ((long long)s * NBATCH * NNODES + node) * 128)
            : (node_emb + node * 128);
        float2 x = *(const float2*)(src + d0);
        xs[s][0] = x.x; xs[s][1] = x.y;
        float ss = x.x * x.x + x.y * x.y;
        float wv = wa.x * rw.x * x.x + wa.y * rw.y * x.y;
        #pragma unroll
        for (int m = 1; m < 64; m <<= 1) {
            ss += __shfl_xor(ss, m);
            wv += __shfl_xor(wv, m);
        }
        lg[s] = wv * rsqrtf(ss * (1.f / 128.f) + 1e-6f);
    }

    float mx = lg[0];
    #pragma unroll
    for (int s = 1; s < 5; ++s) mx = fmaxf(mx, lg[s]);
    float ex[5], sum = 0.f;
    #pragma unroll
    for (int s = 0; s < 5; ++s) { ex[s] = __expf(lg[s] - mx); sum += ex[s]; }
    float inv = 1.f / sum;

    float h0 = 0.f, h1 = 0.f;
    #pragma unroll
    for (int s = 0; s < 5; ++s) {
        float a = ex[s] * inv;
        h0 = fmaf(a, xs[s][0], h0);
        h1 = fmaf(a, xs[s][1], h1);
    }
    *(float2*)(out + node * 128 + d0) = make_float2(h0, h1);
}

// ------------------------------------------------------------------- launcher
extern "C" void kernel_launch(void* const* d_in, const int* in_sizes, int n_in,
                              void* d_out, int out_size, void* d_ws, size_t ws_size,
                              hipStream_t stream)
{
    const float* V      = (const float*)d_in[0];
    const float* E      = (const float*)d_in[1];
    const float* blocks = (const float*)d_in[2];
    const float* We1    = (const float*)d_in[3];
    const float* be1    = (const float*)d_in[4];
    const float* We2    = (const float*)d_in[5];
    const float* be2    = (const float*)d_in[6];
    const float* Wn1    = (const float*)d_in[7];
    const float* bn1    = (const float*)d_in[8];
    const float* Wn2    = (const float*)d_in[9];
    const float* bn2    = (const float*)d_in[10];
    const float* w_attn = (const float*)d_in[11];
    const float* rms_w  = (const float*)d_in[12];
    const int*   edges  = (const int*)d_in[13];
    float* out = (float*)d_out;

    float* ws = (float*)d_ws;
    float* m0sum    = ws;                         // BS*N*64
    float* m1sum    = m0sum + 2097152;
    float* c0       = m1sum + 2097152;
    float* c1       = c0 + 32768;
    float* node_emb = c1 + 32768;                 // BS*N*128
    unsigned short* wbf = (unsigned short*)(node_emb + 4194304);  // 114688 bf16
    unsigned short* w1ef = wbf;            // 16384 (frag-ordered We1 E-part)
    unsigned short* w2f  = wbf + 16384;    // 16384 (frag-ordered We2)
    unsigned short* wp   = wbf + 32768;    // 32768 ([W1s|W1r] transposed)
    unsigned short* wn1t = wbf + 65536;    // 32768
    unsigned short* wn2t = wbf + 98304;    // 16384
    unsigned short* P    = wbf + 114688;   // 32768*256 bf16 partials (16.8MB)

    (void)hipMemsetAsync(d_ws, 0, (size_t)(2097152 * 2 + 32768 * 2) * sizeof(float), stream);

    prep_weights<<<448, 256, 0, stream>>>(We1, We2, Wn1, Wn2, wbf);

    partial_kernel<<<(NBATCH * NNODES) / 64, 256, 0, stream>>>(V, wp, P);

    edge_kernel<<<(NBATCH * NEDGES) / TE, 256, 0, stream>>>(
        E, edges, P, w1ef, be1, w2f, be2, m0sum, m1sum, c0, c1);

    node_kernel<<<(NBATCH * NNODES) / TE, 256, 0, stream>>>(
        V, m0sum, m1sum, c0, c1, wn1t, bn1, wn2t, bn2, node_emb);

    attn_kernel<<<(NBATCH * NNODES) / 4, 256, 0, stream>>>(
        blocks, node_emb, w_attn, rms_w, out);
}

// Round 10
// 376.479 us; speedup vs baseline: 1.3434x; 1.0054x over previous
//
#include <hip/hip_runtime.h>
#include <hip/hip_bf16.h>

#define D 128
#define NNODES 16384
#define NEDGES 262144
#define NBATCH 2
#define TE 64

typedef __attribute__((ext_vector_type(8))) short bf16x8;
typedef __attribute__((ext_vector_type(4))) float f32x4;

__device__ __forceinline__ unsigned short f2bf(float f) {
    unsigned int u = __float_as_uint(f);
    unsigned int r = (u + 0x7fffu + ((u >> 16) & 1u)) >> 16;
    return (unsigned short)r;
}

__device__ __forceinline__ unsigned int pk2bf(float lo, float hi) {
    return (unsigned int)f2bf(lo) | ((unsigned int)f2bf(hi) << 16);
}

__device__ __forceinline__ float bf2f(unsigned short u) {
    return __uint_as_float(((unsigned int)u) << 16);
}

__device__ __forceinline__ bf16x8 pack8(f32x4 a, f32x4 b) {
    unsigned int w0 = pk2bf(a[0], a[1]);
    unsigned int w1 = pk2bf(a[2], a[3]);
    unsigned int w2 = pk2bf(b[0], b[1]);
    unsigned int w3 = pk2bf(b[2], b[3]);
    typedef __attribute__((ext_vector_type(4))) unsigned int u32x4;
    u32x4 u; u.x = w0; u.y = w1; u.z = w2; u.w = w3;
    return __builtin_bit_cast(bf16x8, u);
}

// memory-side packed bf16 atomic add (2 cols per dword-RMW)
__device__ __forceinline__ void atomic_pk(unsigned int* p, unsigned int v) {
    asm volatile("global_atomic_pk_add_bf16 %0, %1, off" :: "v"(p), "v"(v) : "memory");
}

// --------------------------------------------------------------- weight prep
// wbf layout (ushort offsets):
//   w1ef @ 0     : We1 E-part (rows 256..383) in MFMA B-frag order, ks<4
//   w2f  @ 16384 : We2 frag order, ks<4
//   wp   @ 32768 : [W1s|W1r] as [j][k]: wp[j*128+k] = We1[(j<128?k:128+k)][j&127]
//   wn1t @ 65536 : Wn1^T [n][k] k<256
//   wn2t @ 98304 : Wn2^T [n][k] k<128
__global__ __launch_bounds__(256)
void prep_weights(const float* __restrict__ We1, const float* __restrict__ We2,
                  const float* __restrict__ Wn1, const float* __restrict__ Wn2,
                  unsigned short* __restrict__ w)
{
    int id = blockIdx.x * 256 + threadIdx.x;   // 114688 total
    if (id < 16384) {
        int e = id & 7, l = (id >> 3) & 63, nblk = (id >> 9) & 7, ks = id >> 12;
        int k = 256 + ks * 32 + ((l >> 4) & 3) * 8 + e;
        int col = nblk * 16 + (l & 15);
        w[id] = f2bf(We1[k * 128 + col]);
    } else if (id < 32768) {
        int i2 = id - 16384;
        int e = i2 & 7, l = (i2 >> 3) & 63, nblk = (i2 >> 9) & 7, ks = i2 >> 12;
        int k = ks * 32 + ((l >> 4) & 3) * 8 + e;
        int col = nblk * 16 + (l & 15);
        w[id] = f2bf(We2[k * 128 + col]);
    } else if (id < 65536) {
        int i3 = id - 32768;
        int j = i3 >> 7, k = i3 & 127;
        int row = (j < 128) ? k : (128 + k);
        w[id] = f2bf(We1[row * 128 + (j & 127)]);
    } else if (id < 98304) {
        int i4 = id - 65536;
        int n = i4 >> 8, k = i4 & 255;
        w[id] = f2bf(Wn1[k * 128 + n]);
    } else {
        int i5 = id - 98304;
        int n = i5 >> 7, k = i5 & 127;
        w[id] = f2bf(Wn2[k * 128 + n]);
    }
}

// ------------------------------------------------------------ partial kernel
// P[r][j] = sum_k V[r][k] * wp[j][k],  r < 32768, j < 256.
__global__ __launch_bounds__(256)
void partial_kernel(const float* __restrict__ V, const unsigned short* __restrict__ wp,
                    unsigned short* __restrict__ P)
{
    __shared__ unsigned short smem[64 * 136];
    const int t = threadIdx.x, lane = t & 63, wave = t >> 6;
    const int l15 = lane & 15, l4 = lane >> 4;
    const long long r0 = (long long)blockIdx.x * 64;

    for (int i = t; i < 64 * 32; i += 256) {
        int c4 = i & 31, r = i >> 5;
        float4 v = *(const float4*)(V + (r0 + r) * 128 + c4 * 4);
        uint2 p; p.x = pk2bf(v.x, v.y); p.y = pk2bf(v.z, v.w);
        *(uint2*)(&smem[r * 136 + c4 * 4]) = p;
    }
    __syncthreads();

    const int j0 = wave * 64;
    f32x4 acc[4][4] = {};
    const unsigned short* bb0 = wp + (j0 + l15) * 128 + l4 * 8;
    #pragma unroll
    for (int ks = 0; ks < 4; ++ks) {
        bf16x8 bb[4];
        #pragma unroll
        for (int n = 0; n < 4; ++n)
            bb[n] = *(const bf16x8*)(bb0 + n * 16 * 128 + ks * 32);
        #pragma unroll
        for (int mq = 0; mq < 4; ++mq) {
            bf16x8 a = *(const bf16x8*)(&smem[(mq * 16 + l15) * 136 + l4 * 8 + ks * 32]);
            #pragma unroll
            for (int n = 0; n < 4; ++n)
                acc[mq][n] = __builtin_amdgcn_mfma_f32_16x16x32_bf16(a, bb[n], acc[mq][n], 0, 0, 0);
        }
    }
    #pragma unroll
    for (int mq = 0; mq < 4; ++mq) {
        #pragma unroll
        for (int n = 0; n < 4; ++n) {
            #pragma unroll
            for (int i = 0; i < 4; ++i) {
                int row = mq * 16 + l4 * 4 + i;
                int col = j0 + n * 16 + l15;
                P[(r0 + row) * 256 + col] = f2bf(acc[mq][n][i]);
            }
        }
    }
}

// ---------------------------------------------------------------- edge kernel
// r9 structure (direct global->reg E fragments, single barrier) +
// packed-bf16 atomic scatter: xor-1 lane pairs exchange adjacent-column
// values, even lane issues one global_atomic_pk_add_bf16 (2 cols/dword).
// 33.5M dword-RMWs instead of 67M. Sums accumulate in bf16 (ample headroom).
__global__ __launch_bounds__(256)
void edge_kernel(const float* __restrict__ E, const int* __restrict__ edges,
                 const unsigned short* __restrict__ P,
                 const unsigned short* __restrict__ w1ef, const float* __restrict__ be1,
                 const unsigned short* __restrict__ w2f,
                 unsigned short* __restrict__ us_m0, unsigned short* __restrict__ us_m1,
                 float* __restrict__ c0, float* __restrict__ c1)
{
    __shared__ unsigned short Hbuf[TE * 136];

    const int t    = threadIdx.x;
    const int lane = t & 63;
    const int wave = t >> 6;
    const int wr   = wave >> 1;
    const int wc   = wave & 1;
    const int l15  = lane & 15;
    const int l4   = lane >> 4;

    const long long eflat0 = (long long)blockIdx.x * TE;
    const int b  = (int)(eflat0 / NEDGES);
    const long long nb0 = (long long)b * NNODES;

    // degree counts (1M atomics total, negligible)
    if (t < TE) {
        int2 e2 = *(const int2*)(edges + (eflat0 + t) * 2);
        atomicAdd(&c0[nb0 + e2.x], 1.f);
        atomicAdd(&c1[nb0 + e2.y], 1.f);
    }

    // ---- layer 1 (E part): [64x128] @ [128x128], A direct from global ----
    f32x4 acc[2][4] = {};
    {
        const float* er0 = E + (eflat0 + wr * 32 + l15) * D + l4 * 8;
        #pragma unroll
        for (int ks = 0; ks < 4; ++ks) {
            f32x4 xa0 = *(const f32x4*)(er0 + ks * 32);
            f32x4 xb0 = *(const f32x4*)(er0 + ks * 32 + 4);
            f32x4 xa1 = *(const f32x4*)(er0 + 16 * D + ks * 32);
            f32x4 xb1 = *(const f32x4*)(er0 + 16 * D + ks * 32 + 4);
            bf16x8 a0 = pack8(xa0, xb0);
            bf16x8 a1 = pack8(xa1, xb1);
            #pragma unroll
            for (int n = 0; n < 4; ++n) {
                bf16x8 bb = *(const bf16x8*)(w1ef + (((ks * 8 + wc * 4 + n) * 64 + lane) << 3));
                acc[0][n] = __builtin_amdgcn_mfma_f32_16x16x32_bf16(a0, bb, acc[0][n], 0, 0, 0);
                acc[1][n] = __builtin_amdgcn_mfma_f32_16x16x32_bf16(a1, bb, acc[1][n], 0, 0, 0);
            }
        }
    }

    // node indices for epilogue/scatter: per-lane int2 loads (512B block, L1)
    int nd0[2][4], nd1[2][4];
    #pragma unroll
    for (int m = 0; m < 2; ++m) {
        #pragma unroll
        for (int i = 0; i < 4; ++i) {
            int row = wr * 32 + m * 16 + l4 * 4 + i;
            int2 e2 = *(const int2*)(edges + (eflat0 + row) * 2);
            nd0[m][i] = e2.x;
            nd1[m][i] = e2.y;
        }
    }

    // epilogue: + P[snd] + P[rcv] + bias, silu -> Hbuf
    #pragma unroll
    for (int n = 0; n < 4; ++n) {
        int col = wc * 64 + n * 16 + l15;
        float bias = be1[col];
        #pragma unroll
        for (int m = 0; m < 2; ++m) {
            #pragma unroll
            for (int i = 0; i < 4; ++i) {
                int row = wr * 32 + m * 16 + l4 * 4 + i;
                float a = acc[m][n][i] + bias
                        + bf2f(P[(nb0 + nd0[m][i]) * 256 + col])
                        + bf2f(P[(nb0 + nd1[m][i]) * 256 + 128 + col]);
                Hbuf[row * 136 + col] = f2bf(a / (1.f + __expf(-a)));
            }
        }
    }
    __syncthreads();   // single barrier: H handoff

    // ---- layer 2: [64x128] @ [128x128] ----
    f32x4 acc2[2][4] = {};
    {
        const unsigned short* hrow = &Hbuf[(wr * 32 + l15) * 136 + l4 * 8];
        #pragma unroll
        for (int ks = 0; ks < 4; ++ks) {
            bf16x8 a0 = *(const bf16x8*)(hrow + ks * 32);
            bf16x8 a1 = *(const bf16x8*)(hrow + 16 * 136 + ks * 32);
            #pragma unroll
            for (int n = 0; n < 4; ++n) {
                bf16x8 bb = *(const bf16x8*)(w2f + (((ks * 8 + wc * 4 + n) * 64 + lane) << 3));
                acc2[0][n] = __builtin_amdgcn_mfma_f32_16x16x32_bf16(a0, bb, acc2[0][n], 0, 0, 0);
                acc2[1][n] = __builtin_amdgcn_mfma_f32_16x16x32_bf16(a1, bb, acc2[1][n], 0, 0, 0);
            }
        }
    }

    // scatter: packed bf16 atomics. xor-1 lane pair = same edge, adjacent
    // cols; even lane adds (col, col+1) in one dword-RMW. NOTE: be2 is NOT
    // added here (mean(x+b)=mean(x)+b; added in node kernel, count-gated).
    {
        unsigned short* dst_arr = wc ? us_m1 : us_m0;
        #pragma unroll
        for (int n = 0; n < 4; ++n) {
            int colh = n * 16 + l15;
            #pragma unroll
            for (int m = 0; m < 2; ++m) {
                #pragma unroll
                for (int i = 0; i < 4; ++i) {
                    int node = wc ? nd1[m][i] : nd0[m][i];
                    float v  = acc2[m][n][i];
                    float vn = __shfl_xor(v, 1);
                    if (!(lane & 1)) {
                        atomic_pk((unsigned int*)(dst_arr + (nb0 + node) * 64 + colh),
                                  pk2bf(v, vn));
                    }
                }
            }
        }
    }
}

// ---------------------------------------------------------------- node kernel
// m0/m1 now bf16 sums; divide by count and add be2 (count-gated) at staging.
__global__ __launch_bounds__(256)
void node_kernel(const float* __restrict__ V,
                 const unsigned short* __restrict__ m0, const unsigned short* __restrict__ m1,
                 const float* __restrict__ c0, const float* __restrict__ c1,
                 const float* __restrict__ be2,
                 const unsigned short* __restrict__ wn1t, const float* __restrict__ bn1,
                 const unsigned short* __restrict__ wn2t, const float* __restrict__ bn2,
                 float* __restrict__ node_emb)
{
    __shared__ unsigned short smem[TE * 264];   // A [64][264]; reused as H [64][136]

    const int t    = threadIdx.x;
    const int lane = t & 63;
    const int wave = t >> 6;
    const int wr   = wave >> 1;
    const int wc   = wave & 1;
    const int l15  = lane & 15;
    const int l4   = lane >> 4;

    const long long nflat0 = (long long)blockIdx.x * TE;

    for (int i = t; i < TE * 48; i += 256) {
        int n  = i / 48;
        int c4 = i - n * 48;
        long long node = nflat0 + n;
        if (c4 < 32) {
            float4 v = *(const float4*)(V + node * 128 + c4 * 4);
            uint2 p; p.x = pk2bf(v.x, v.y); p.y = pk2bf(v.z, v.w);
            *(uint2*)(&smem[n * 264 + c4 * 4]) = p;
        } else {
            int dir = (c4 >= 40);
            int j = c4 - 32 - dir * 8;
            const unsigned short* src = dir ? m1 : m0;
            float cnt = (dir ? c1 : c0)[node];
            float inv = 1.f / fmaxf(cnt, 1.f);
            float bon = (cnt >= 1.f) ? 1.f : 0.f;     // zero-degree: mean=0, no bias
            uint4 raw = *(const uint4*)(src + node * 64 + j * 8);
            const float* bb = be2 + dir * 64 + j * 8;
            unsigned int rr[4] = {raw.x, raw.y, raw.z, raw.w};
            unsigned int o[4];
            #pragma unroll
            for (int q = 0; q < 4; ++q) {
                float lo = bf2f((unsigned short)(rr[q] & 0xffffu)) * inv + bb[2 * q] * bon;
                float hi = bf2f((unsigned short)(rr[q] >> 16)) * inv + bb[2 * q + 1] * bon;
                o[q] = pk2bf(lo, hi);
            }
            uint4 st; st.x = o[0]; st.y = o[1]; st.z = o[2]; st.w = o[3];
            *(uint4*)(&smem[n * 264 + 128 + dir * 64 + j * 8]) = st;
        }
    }
    __syncthreads();

    f32x4 acc[2][4] = {};
    {
        const unsigned short* arow = &smem[(wr * 32 + l15) * 264 + l4 * 8];
        const unsigned short* bb0  = wn1t + (wc * 64 + l15) * 256 + l4 * 8;
        for (int ks = 0; ks < 8; ++ks) {
            bf16x8 a0 = *(const bf16x8*)(arow + ks * 32);
            bf16x8 a1 = *(const bf16x8*)(arow + 16 * 264 + ks * 32);
            #pragma unroll
            for (int n = 0; n < 4; ++n) {
                bf16x8 bb = *(const bf16x8*)(bb0 + n * 16 * 256 + ks * 32);
                acc[0][n] = __builtin_amdgcn_mfma_f32_16x16x32_bf16(a0, bb, acc[0][n], 0, 0, 0);
                acc[1][n] = __builtin_amdgcn_mfma_f32_16x16x32_bf16(a1, bb, acc[1][n], 0, 0, 0);
            }
        }
    }
    __syncthreads();

    #pragma unroll
    for (int n = 0; n < 4; ++n) {
        int col = wc * 64 + n * 16 + l15;
        float bias = bn1[col];
        #pragma unroll
        for (int m = 0; m < 2; ++m) {
            #pragma unroll
            for (int i = 0; i < 4; ++i) {
                int row = wr * 32 + m * 16 + l4 * 4 + i;
                float a = acc[m][n][i] + bias;
                smem[row * 136 + col] = f2bf(a / (1.f + __expf(-a)));
            }
        }
    }
    __syncthreads();

    f32x4 acc2[2][4] = {};
    {
        const unsigned short* hrow = &smem[(wr * 32 + l15) * 136 + l4 * 8];
        const unsigned short* bb0  = wn2t + (wc * 64 + l15) * 128 + l4 * 8;
        #pragma unroll
        for (int ks = 0; ks < 4; ++ks) {
            bf16x8 a0 = *(const bf16x8*)(hrow + ks * 32);
            bf16x8 a1 = *(const bf16x8*)(hrow + 16 * 136 + ks * 32);
            #pragma unroll
            for (int n = 0; n < 4; ++n) {
                bf16x8 bb = *(const bf16x8*)(bb0 + n * 16 * 128 + ks * 32);
                acc2[0][n] = __builtin_amdgcn_mfma_f32_16x16x32_bf16(a0, bb, acc2[0][n], 0, 0, 0);
                acc2[1][n] = __builtin_amdgcn_mfma_f32_16x16x32_bf16(a1, bb, acc2[1][n], 0, 0, 0);
            }
        }
    }

    #pragma unroll
    for (int n = 0; n < 4; ++n) {
        int col = wc * 64 + n * 16 + l15;
        float bias = bn2[col];
        #pragma unroll
        for (int m = 0; m < 2; ++m) {
            #pragma unroll
            for (int i = 0; i < 4; ++i) {
                long long row = nflat0 + wr * 32 + m * 16 + l4 * 4 + i;
                node_emb[row * 128 + col] = acc2[m][n][i] + bias;
            }
        }
    }
}

// ------------------------------------------------------------ attention kernel
__global__ __launch_bounds__(256)
void attn_kernel(const float* __restrict__ blocks, const float* __restrict__ node_emb,
                 const float* __restrict__ w_attn, const float* __restrict__ rms_w,
                 float* __restrict__ out)
{
    const int t    = threadIdx.x;
    const int wave = t >> 6;
    const int lane = t & 63;
    const long long node = (long long)blockIdx.x * 4 + wave;
    const int d0 = lane * 2;

    float2 wa = *(const float2*)(w_attn + d0);
    float2 rw = *(const float2*)(rms_w + d0);

    float xs[5][2];
    float lg[5];
    #pragma unroll
    for (int s = 0; s < 5; ++s) {
        const float* src = (s < 4)
            ? (blocks + ((long long)s * NBATCH * NNODES + node) * 128)
            : (node_emb + node * 128);
        float2 x = *(const float2*)(src + d0);
        xs[s][0] = x.x; xs[s][1] = x.y;
        float ss = x.x * x.x + x.y * x.y;
        float wv = wa.x * rw.x * x.x + wa.y * rw.y * x.y;
        #pragma unroll
        for (int m = 1; m < 64; m <<= 1) {
            ss += __shfl_xor(ss, m);
            wv += __shfl_xor(wv, m);
        }
        lg[s] = wv * rsqrtf(ss * (1.f / 128.f) + 1e-6f);
    }

    float mx = lg[0];
    #pragma unroll
    for (int s = 1; s < 5; ++s) mx = fmaxf(mx, lg[s]);
    float ex[5], sum = 0.f;
    #pragma unroll
    for (int s = 0; s < 5; ++s) { ex[s] = __expf(lg[s] - mx); sum += ex[s]; }
    float inv = 1.f / sum;

    float h0 = 0.f, h1 = 0.f;
    #pragma unroll
    for (int s = 0; s < 5; ++s) {
        float a = ex[s] * inv;
        h0 = fmaf(a, xs[s][0], h0);
        h1 = fmaf(a, xs[s][1], h1);
    }
    *(float2*)(out + node * 128 + d0) = make_float2(h0, h1);
}

// ------------------------------------------------------------------- launcher
extern "C" void kernel_launch(void* const* d_in, const int* in_sizes, int n_in,
                              void* d_out, int out_size, void* d_ws, size_t ws_size,
                              hipStream_t stream)
{
    const float* V      = (const float*)d_in[0];
    const float* E      = (const float*)d_in[1];
    const float* blocks = (const float*)d_in[2];
    const float* We1    = (const float*)d_in[3];
    const float* be1    = (const float*)d_in[4];
    const float* We2    = (const float*)d_in[5];
    const float* be2    = (const float*)d_in[6];
    const float* Wn1    = (const float*)d_in[7];
    const float* bn1    = (const float*)d_in[8];
    const float* Wn2    = (const float*)d_in[9];
    const float* bn2    = (const float*)d_in[10];
    const float* w_attn = (const float*)d_in[11];
    const float* rms_w  = (const float*)d_in[12];
    const int*   edges  = (const int*)d_in[13];
    float* out = (float*)d_out;

    // ws layout: [us_m0 bf16 4MB][us_m1 bf16 4MB][c0 128KB][c1 128KB]
    //            [node_emb f32 16MB][wbf 224KB][P bf16 16.8MB]
    unsigned short* us_m0 = (unsigned short*)d_ws;          // 2097152 ushort
    unsigned short* us_m1 = us_m0 + 2097152;
    float* c0       = (float*)(us_m1 + 2097152);
    float* c1       = c0 + 32768;
    float* node_emb = c1 + 32768;
    unsigned short* wbf = (unsigned short*)(node_emb + 4194304);  // 114688 bf16
    unsigned short* w1ef = wbf;            // 16384 (frag-ordered We1 E-part)
    unsigned short* w2f  = wbf + 16384;    // 16384 (frag-ordered We2)
    unsigned short* wp   = wbf + 32768;    // 32768 ([W1s|W1r] transposed)
    unsigned short* wn1t = wbf + 65536;    // 32768
    unsigned short* wn2t = wbf + 98304;    // 16384
    unsigned short* P    = wbf + 114688;   // 32768*256 bf16 partials (16.8MB)

    // zero bf16 accumulators + counts (8MB + 256KB)
    (void)hipMemsetAsync(d_ws, 0, (size_t)(2097152 * 2 * 2 + 32768 * 2 * 4), stream);

    prep_weights<<<448, 256, 0, stream>>>(We1, We2, Wn1, Wn2, wbf);

    partial_kernel<<<(NBATCH * NNODES) / 64, 256, 0, stream>>>(V, wp, P);

    edge_kernel<<<(NBATCH * NEDGES) / TE, 256, 0, stream>>>(
        E, edges, P, w1ef, be1, w2f, us_m0, us_m1, c0, c1);

    node_kernel<<<(NBATCH * NNODES) / TE, 256, 0, stream>>>(
        V, us_m0, us_m1, c0, c1, be2, wn1t, bn1, wn2t, bn2, node_emb);

    attn_kernel<<<(NBATCH * NNODES) / 4, 256, 0, stream>>>(
        blocks, node_emb, w_attn, rms_w, out);
}

// Round 11
// 364.871 us; speedup vs baseline: 1.3862x; 1.0318x over previous
//
#include <hip/hip_runtime.h>
#include <hip/hip_bf16.h>

#define D 128
#define NNODES 16384
#define NEDGES 262144
#define NBATCH 2
#define TE 128

typedef __attribute__((ext_vector_type(8))) short bf16x8;
typedef __attribute__((ext_vector_type(4))) float f32x4;

__device__ __forceinline__ unsigned short f2bf(float f) {
    unsigned int u = __float_as_uint(f);
    unsigned int r = (u + 0x7fffu + ((u >> 16) & 1u)) >> 16;
    return (unsigned short)r;
}

__device__ __forceinline__ unsigned int pk2bf(float lo, float hi) {
    return (unsigned int)f2bf(lo) | ((unsigned int)f2bf(hi) << 16);
}

__device__ __forceinline__ float bf2f(unsigned short u) {
    return __uint_as_float(((unsigned int)u) << 16);
}

__device__ __forceinline__ float bflo(unsigned int u) {
    return __uint_as_float(u << 16);
}
__device__ __forceinline__ float bfhi(unsigned int u) {
    return __uint_as_float(u & 0xffff0000u);
}

__device__ __forceinline__ bf16x8 pack8(f32x4 a, f32x4 b) {
    unsigned int w0 = pk2bf(a[0], a[1]);
    unsigned int w1 = pk2bf(a[2], a[3]);
    unsigned int w2 = pk2bf(b[0], b[1]);
    unsigned int w3 = pk2bf(b[2], b[3]);
    typedef __attribute__((ext_vector_type(4))) unsigned int u32x4;
    u32x4 u; u.x = w0; u.y = w1; u.z = w2; u.w = w3;
    return __builtin_bit_cast(bf16x8, u);
}

// memory-side packed bf16 atomic add (2 cols per dword-RMW)
__device__ __forceinline__ void atomic_pk(unsigned int* p, unsigned int v) {
    asm volatile("global_atomic_pk_add_bf16 %0, %1, off" :: "v"(p), "v"(v) : "memory");
}

// --------------------------------------------------------------- weight prep
// wbf layout (ushort offsets):
//   w1ef @ 0     : We1 E-part (rows 256..383) in MFMA B-frag order, ks<4
//   w2f  @ 16384 : We2 frag order, ks<4
//   wp   @ 32768 : [W1s|W1r] as [j][k]: wp[j*128+k] = We1[(j<128?k:128+k)][j&127]
//   wn1t @ 65536 : Wn1^T [n][k] k<256
//   wn2t @ 98304 : Wn2^T [n][k] k<128
__global__ __launch_bounds__(256)
void prep_weights(const float* __restrict__ We1, const float* __restrict__ We2,
                  const float* __restrict__ Wn1, const float* __restrict__ Wn2,
                  unsigned short* __restrict__ w)
{
    int id = blockIdx.x * 256 + threadIdx.x;   // 114688 total
    if (id < 16384) {
        int e = id & 7, l = (id >> 3) & 63, nblk = (id >> 9) & 7, ks = id >> 12;
        int k = 256 + ks * 32 + ((l >> 4) & 3) * 8 + e;
        int col = nblk * 16 + (l & 15);
        w[id] = f2bf(We1[k * 128 + col]);
    } else if (id < 32768) {
        int i2 = id - 16384;
        int e = i2 & 7, l = (i2 >> 3) & 63, nblk = (i2 >> 9) & 7, ks = i2 >> 12;
        int k = ks * 32 + ((l >> 4) & 3) * 8 + e;
        int col = nblk * 16 + (l & 15);
        w[id] = f2bf(We2[k * 128 + col]);
    } else if (id < 65536) {
        int i3 = id - 32768;
        int j = i3 >> 7, k = i3 & 127;
        int row = (j < 128) ? k : (128 + k);
        w[id] = f2bf(We1[row * 128 + (j & 127)]);
    } else if (id < 98304) {
        int i4 = id - 65536;
        int n = i4 >> 8, k = i4 & 255;
        w[id] = f2bf(Wn1[k * 128 + n]);
    } else {
        int i5 = id - 98304;
        int n = i5 >> 7, k = i5 & 127;
        w[id] = f2bf(Wn2[k * 128 + n]);
    }
}

// ------------------------------------------------------------ partial kernel
// P2[r][pcol]: PERMUTED layout so the 4 cols a lane needs are adjacent:
//   original col = part*128 + sub*64 + n*16 + l15  (part: 0=snd,1=rcv)
//   stored at      part*128 + sub*64 + l15*4 + n
__global__ __launch_bounds__(256)
void partial_kernel(const float* __restrict__ V, const unsigned short* __restrict__ wp,
                    unsigned short* __restrict__ P)
{
    __shared__ unsigned short smem[64 * 136];
    const int t = threadIdx.x, lane = t & 63, wave = t >> 6;
    const int l15 = lane & 15, l4 = lane >> 4;
    const long long r0 = (long long)blockIdx.x * 64;

    for (int i = t; i < 64 * 32; i += 256) {
        int c4 = i & 31, r = i >> 5;
        float4 v = *(const float4*)(V + (r0 + r) * 128 + c4 * 4);
        uint2 p; p.x = pk2bf(v.x, v.y); p.y = pk2bf(v.z, v.w);
        *(uint2*)(&smem[r * 136 + c4 * 4]) = p;
    }
    __syncthreads();

    const int j0 = wave * 64;
    f32x4 acc[4][4] = {};
    const unsigned short* bb0 = wp + (j0 + l15) * 128 + l4 * 8;
    #pragma unroll
    for (int ks = 0; ks < 4; ++ks) {
        bf16x8 bb[4];
        #pragma unroll
        for (int n = 0; n < 4; ++n)
            bb[n] = *(const bf16x8*)(bb0 + n * 16 * 128 + ks * 32);
        #pragma unroll
        for (int mq = 0; mq < 4; ++mq) {
            bf16x8 a = *(const bf16x8*)(&smem[(mq * 16 + l15) * 136 + l4 * 8 + ks * 32]);
            #pragma unroll
            for (int n = 0; n < 4; ++n)
                acc[mq][n] = __builtin_amdgcn_mfma_f32_16x16x32_bf16(a, bb[n], acc[mq][n], 0, 0, 0);
        }
    }
    const int pbase = (wave >> 1) * 128 + (wave & 1) * 64 + l15 * 4;
    #pragma unroll
    for (int mq = 0; mq < 4; ++mq) {
        #pragma unroll
        for (int n = 0; n < 4; ++n) {
            #pragma unroll
            for (int i = 0; i < 4; ++i) {
                int row = mq * 16 + l4 * 4 + i;
                P[(r0 + row) * 256 + pbase + n] = f2bf(acc[mq][n][i]);
            }
        }
    }
}

// ---------------------------------------------------------------- edge kernel
// 128 edges/block, 8 waves (4 row-blocks x 2 col-blocks), 512 threads.
// E fragments direct global->reg; P gather = 16x 8B dwordx2 per thread
// (permuted P layout), issued in one batch; single barrier (H handoff);
// packed-bf16 atomic scatter.
__global__ __launch_bounds__(512)
void edge_kernel(const float* __restrict__ E, const int* __restrict__ edges,
                 const unsigned short* __restrict__ P,
                 const unsigned short* __restrict__ w1ef, const float* __restrict__ be1,
                 const unsigned short* __restrict__ w2f,
                 unsigned short* __restrict__ us_m0, unsigned short* __restrict__ us_m1,
                 float* __restrict__ c0, float* __restrict__ c1)
{
    __shared__ unsigned short Hbuf[TE * 136];

    const int t    = threadIdx.x;
    const int lane = t & 63;
    const int wave = t >> 6;
    const int wr   = wave >> 1;          // 0..3 (32-edge row block)
    const int wc   = wave & 1;           // 0..1 (64-col block)
    const int l15  = lane & 15;
    const int l4   = lane >> 4;

    const long long eflat0 = (long long)blockIdx.x * TE;
    const int b  = (int)(eflat0 / NEDGES);
    const long long nb0 = (long long)b * NNODES;

    // degree counts
    if (t < TE) {
        int2 e2 = *(const int2*)(edges + (eflat0 + t) * 2);
        atomicAdd(&c0[nb0 + e2.x], 1.f);
        atomicAdd(&c1[nb0 + e2.y], 1.f);
    }

    // ---- layer 1 (E part): [128x128] @ [128x128], A direct from global ----
    f32x4 acc[2][4] = {};
    {
        const float* er0 = E + (eflat0 + wr * 32 + l15) * D + l4 * 8;
        #pragma unroll
        for (int ks = 0; ks < 4; ++ks) {
            f32x4 xa0 = *(const f32x4*)(er0 + ks * 32);
            f32x4 xb0 = *(const f32x4*)(er0 + ks * 32 + 4);
            f32x4 xa1 = *(const f32x4*)(er0 + 16 * D + ks * 32);
            f32x4 xb1 = *(const f32x4*)(er0 + 16 * D + ks * 32 + 4);
            bf16x8 a0 = pack8(xa0, xb0);
            bf16x8 a1 = pack8(xa1, xb1);
            #pragma unroll
            for (int n = 0; n < 4; ++n) {
                bf16x8 bb = *(const bf16x8*)(w1ef + (((ks * 8 + wc * 4 + n) * 64 + lane) << 3));
                acc[0][n] = __builtin_amdgcn_mfma_f32_16x16x32_bf16(a0, bb, acc[0][n], 0, 0, 0);
                acc[1][n] = __builtin_amdgcn_mfma_f32_16x16x32_bf16(a1, bb, acc[1][n], 0, 0, 0);
            }
        }
    }

    // node indices (per-lane int2, L1-hot)
    int nd0[2][4], nd1[2][4];
    #pragma unroll
    for (int m = 0; m < 2; ++m) {
        #pragma unroll
        for (int i = 0; i < 4; ++i) {
            int row = wr * 32 + m * 16 + l4 * 4 + i;
            int2 e2 = *(const int2*)(edges + (eflat0 + row) * 2);
            nd0[m][i] = e2.x;
            nd1[m][i] = e2.y;
        }
    }

    // ---- P gather: permuted layout -> one dwordx2 per (edge, part) ----
    const unsigned short* Pb = P + nb0 * 256;
    const unsigned int wcl = wc * 64 + l15 * 4;
    uint2 su[2][4], ru[2][4];
    #pragma unroll
    for (int m = 0; m < 2; ++m) {
        #pragma unroll
        for (int i = 0; i < 4; ++i) {
            su[m][i] = *(const uint2*)(Pb + (unsigned)nd0[m][i] * 256u + wcl);
            ru[m][i] = *(const uint2*)(Pb + (unsigned)nd1[m][i] * 256u + 128u + wcl);
        }
    }

    // epilogue: + P_s + P_r + bias, silu -> Hbuf
    float bia[4];
    #pragma unroll
    for (int n = 0; n < 4; ++n) bia[n] = be1[wc * 64 + n * 16 + l15];
    #pragma unroll
    for (int m = 0; m < 2; ++m) {
        #pragma unroll
        for (int i = 0; i < 4; ++i) {
            int row = wr * 32 + m * 16 + l4 * 4 + i;
            float ps[4] = { bflo(su[m][i].x), bfhi(su[m][i].x),
                            bflo(su[m][i].y), bfhi(su[m][i].y) };
            float pr[4] = { bflo(ru[m][i].x), bfhi(ru[m][i].x),
                            bflo(ru[m][i].y), bfhi(ru[m][i].y) };
            #pragma unroll
            for (int n = 0; n < 4; ++n) {
                float a = acc[m][n][i] + bia[n] + ps[n] + pr[n];
                Hbuf[row * 136 + wc * 64 + n * 16 + l15] = f2bf(a / (1.f + __expf(-a)));
            }
        }
    }
    __syncthreads();   // single barrier: H handoff

    // ---- layer 2: [128x128] @ [128x128] ----
    f32x4 acc2[2][4] = {};
    {
        const unsigned short* hrow = &Hbuf[(wr * 32 + l15) * 136 + l4 * 8];
        #pragma unroll
        for (int ks = 0; ks < 4; ++ks) {
            bf16x8 a0 = *(const bf16x8*)(hrow + ks * 32);
            bf16x8 a1 = *(const bf16x8*)(hrow + 16 * 136 + ks * 32);
            #pragma unroll
            for (int n = 0; n < 4; ++n) {
                bf16x8 bb = *(const bf16x8*)(w2f + (((ks * 8 + wc * 4 + n) * 64 + lane) << 3));
                acc2[0][n] = __builtin_amdgcn_mfma_f32_16x16x32_bf16(a0, bb, acc2[0][n], 0, 0, 0);
                acc2[1][n] = __builtin_amdgcn_mfma_f32_16x16x32_bf16(a1, bb, acc2[1][n], 0, 0, 0);
            }
        }
    }

    // scatter: packed bf16 atomics (xor-1 lane pairs, even lane issues)
    {
        unsigned short* dst_arr = wc ? us_m1 : us_m0;
        #pragma unroll
        for (int n = 0; n < 4; ++n) {
            int colh = n * 16 + l15;
            #pragma unroll
            for (int m = 0; m < 2; ++m) {
                #pragma unroll
                for (int i = 0; i < 4; ++i) {
                    int node = wc ? nd1[m][i] : nd0[m][i];
                    float v  = acc2[m][n][i];
                    float vn = __shfl_xor(v, 1);
                    if (!(lane & 1)) {
                        atomic_pk((unsigned int*)(dst_arr + (nb0 + node) * 64 + colh),
                                  pk2bf(v, vn));
                    }
                }
            }
        }
    }
}

// ---------------------------------------------------------------- node kernel
// m0/m1 bf16 sums; divide by count and add be2 (count-gated) at staging.
__global__ __launch_bounds__(256)
void node_kernel(const float* __restrict__ V,
                 const unsigned short* __restrict__ m0, const unsigned short* __restrict__ m1,
                 const float* __restrict__ c0, const float* __restrict__ c1,
                 const float* __restrict__ be2,
                 const unsigned short* __restrict__ wn1t, const float* __restrict__ bn1,
                 const unsigned short* __restrict__ wn2t, const float* __restrict__ bn2,
                 float* __restrict__ node_emb)
{
    __shared__ unsigned short smem[64 * 264];   // A [64][264]; reused as H [64][136]

    const int t    = threadIdx.x;
    const int lane = t & 63;
    const int wave = t >> 6;
    const int wr   = wave >> 1;
    const int wc   = wave & 1;
    const int l15  = lane & 15;
    const int l4   = lane >> 4;

    const long long nflat0 = (long long)blockIdx.x * 64;

    for (int i = t; i < 64 * 48; i += 256) {
        int n  = i / 48;
        int c4 = i - n * 48;
        long long node = nflat0 + n;
        if (c4 < 32) {
            float4 v = *(const float4*)(V + node * 128 + c4 * 4);
            uint2 p; p.x = pk2bf(v.x, v.y); p.y = pk2bf(v.z, v.w);
            *(uint2*)(&smem[n * 264 + c4 * 4]) = p;
        } else {
            int dir = (c4 >= 40);
            int j = c4 - 32 - dir * 8;
            const unsigned short* src = dir ? m1 : m0;
            float cnt = (dir ? c1 : c0)[node];
            float inv = 1.f / fmaxf(cnt, 1.f);
            float bon = (cnt >= 1.f) ? 1.f : 0.f;     // zero-degree: mean=0, no bias
            uint4 raw = *(const uint4*)(src + node * 64 + j * 8);
            const float* bb = be2 + dir * 64 + j * 8;
            unsigned int rr[4] = {raw.x, raw.y, raw.z, raw.w};
            unsigned int o[4];
            #pragma unroll
            for (int q = 0; q < 4; ++q) {
                float lo = bflo(rr[q]) * inv + bb[2 * q] * bon;
                float hi = bfhi(rr[q]) * inv + bb[2 * q + 1] * bon;
                o[q] = pk2bf(lo, hi);
            }
            uint4 st; st.x = o[0]; st.y = o[1]; st.z = o[2]; st.w = o[3];
            *(uint4*)(&smem[n * 264 + 128 + dir * 64 + j * 8]) = st;
        }
    }
    __syncthreads();

    f32x4 acc[2][4] = {};
    {
        const unsigned short* arow = &smem[(wr * 32 + l15) * 264 + l4 * 8];
        const unsigned short* bb0  = wn1t + (wc * 64 + l15) * 256 + l4 * 8;
        for (int ks = 0; ks < 8; ++ks) {
            bf16x8 a0 = *(const bf16x8*)(arow + ks * 32);
            bf16x8 a1 = *(const bf16x8*)(arow + 16 * 264 + ks * 32);
            #pragma unroll
            for (int n = 0; n < 4; ++n) {
                bf16x8 bb = *(const bf16x8*)(bb0 + n * 16 * 256 + ks * 32);
                acc[0][n] = __builtin_amdgcn_mfma_f32_16x16x32_bf16(a0, bb, acc[0][n], 0, 0, 0);
                acc[1][n] = __builtin_amdgcn_mfma_f32_16x16x32_bf16(a1, bb, acc[1][n], 0, 0, 0);
            }
        }
    }
    __syncthreads();

    #pragma unroll
    for (int n = 0; n < 4; ++n) {
        int col = wc * 64 + n * 16 + l15;
        float bias = bn1[col];
        #pragma unroll
        for (int m = 0; m < 2; ++m) {
            #pragma unroll
            for (int i = 0; i < 4; ++i) {
                int row = wr * 32 + m * 16 + l4 * 4 + i;
                float a = acc[m][n][i] + bias;
                smem[row * 136 + col] = f2bf(a / (1.f + __expf(-a)));
            }
        }
    }
    __syncthreads();

    f32x4 acc2[2][4] = {};
    {
        const unsigned short* hrow = &smem[(wr * 32 + l15) * 136 + l4 * 8];
        const unsigned short* bb0  = wn2t + (wc * 64 + l15) * 128 + l4 * 8;
        #pragma unroll
        for (int ks = 0; ks < 4; ++ks) {
            bf16x8 a0 = *(const bf16x8*)(hrow + ks * 32);
            bf16x8 a1 = *(const bf16x8*)(hrow + 16 * 136 + ks * 32);
            #pragma unroll
            for (int n = 0; n < 4; ++n) {
                bf16x8 bb = *(const bf16x8*)(bb0 + n * 16 * 128 + ks * 32);
                acc2[0][n] = __builtin_amdgcn_mfma_f32_16x16x32_bf16(a0, bb, acc2[0][n], 0, 0, 0);
                acc2[1][n] = __builtin_amdgcn_mfma_f32_16x16x32_bf16(a1, bb, acc2[1][n], 0, 0, 0);
            }
        }
    }

    #pragma unroll
    for (int n = 0; n < 4; ++n) {
        int col = wc * 64 + n * 16 + l15;
        float bias = bn2[col];
        #pragma unroll
        for (int m = 0; m < 2; ++m) {
            #pragma unroll
            for (int i = 0; i < 4; ++i) {
                long long row = nflat0 + wr * 32 + m * 16 + l4 * 4 + i;
                node_emb[row * 128 + col] = acc2[m][n][i] + bias;
            }
        }
    }
}

// ------------------------------------------------------------ attention kernel
__global__ __launch_bounds__(256)
void attn_kernel(const float* __restrict__ blocks, const float* __restrict__ node_emb,
                 const float* __restrict__ w_attn, const float* __restrict__ rms_w,
                 float* __restrict__ out)
{
    const int t    = threadIdx.x;
    const int wave = t >> 6;
    const int lane = t & 63;
    const long long node = (long long)blockIdx.x * 4 + wave;
    const int d0 = lane * 2;

    float2 wa = *(const float2*)(w_attn + d0);
    float2 rw = *(const float2*)(rms_w + d0);

    float xs[5][2];
    float lg[5];
    #pragma unroll
    for (int s = 0; s < 5; ++s) {
        const float* src = (s < 4)
            ? (blocks + ((long long)s * NBATCH * NNODES + node) * 128)
            : (node_emb + node * 128);
        float2 x = *(const float2*)(src + d0);
        xs[s][0] = x.x; xs[s][1] = x.y;
        float ss = x.x * x.x + x.y * x.y;
        float wv = wa.x * rw.x * x.x + wa.y * rw.y * x.y;
        #pragma unroll
        for (int m = 1; m < 64; m <<= 1) {
            ss += __shfl_xor(ss, m);
            wv += __shfl_xor(wv, m);
        }
        lg[s] = wv * rsqrtf(ss * (1.f / 128.f) + 1e-6f);
    }

    float mx = lg[0];
    #pragma unroll
    for (int s = 1; s < 5; ++s) mx = fmaxf(mx, lg[s]);
    float ex[5], sum = 0.f;
    #pragma unroll
    for (int s = 0; s < 5; ++s) { ex[s] = __expf(lg[s] - mx); sum += ex[s]; }
    float inv = 1.f / sum;

    float h0 = 0.f, h1 = 0.f;
    #pragma unroll
    for (int s = 0; s < 5; ++s) {
        float a = ex[s] * inv;
        h0 = fmaf(a, xs[s][0], h0);
        h1 = fmaf(a, xs[s][1], h1);
    }
    *(float2*)(out + node * 128 + d0) = make_float2(h0, h1);
}

// ------------------------------------------------------------------- launcher
extern "C" void kernel_launch(void* const* d_in, const int* in_sizes, int n_in,
                              void* d_out, int out_size, void* d_ws, size_t ws_size,
                              hipStream_t stream)
{
    const float* V      = (const float*)d_in[0];
    const float* E      = (const float*)d_in[1];
    const float* blocks = (const float*)d_in[2];
    const float* We1    = (const float*)d_in[3];
    const float* be1    = (const float*)d_in[4];
    const float* We2    = (const float*)d_in[5];
    const float* be2    = (const float*)d_in[6];
    const float* Wn1    = (const float*)d_in[7];
    const float* bn1    = (const float*)d_in[8];
    const float* Wn2    = (const float*)d_in[9];
    const float* bn2    = (const float*)d_in[10];
    const float* w_attn = (const float*)d_in[11];
    const float* rms_w  = (const float*)d_in[12];
    const int*   edges  = (const int*)d_in[13];
    float* out = (float*)d_out;

    // ws layout: [us_m0 bf16 4MB][us_m1 bf16 4MB][c0 128KB][c1 128KB]
    //            [node_emb f32 16MB][wbf 224KB][P bf16 16.8MB]
    unsigned short* us_m0 = (unsigned short*)d_ws;          // 2097152 ushort
    unsigned short* us_m1 = us_m0 + 2097152;
    float* c0       = (float*)(us_m1 + 2097152);
    float* c1       = c0 + 32768;
    float* node_emb = c1 + 32768;
    unsigned short* wbf = (unsigned short*)(node_emb + 4194304);  // 114688 bf16
    unsigned short* w1ef = wbf;            // 16384 (frag-ordered We1 E-part)
    unsigned short* w2f  = wbf + 16384;    // 16384 (frag-ordered We2)
    unsigned short* wp   = wbf + 32768;    // 32768 ([W1s|W1r] transposed)
    unsigned short* wn1t = wbf + 65536;    // 32768
    unsigned short* wn2t = wbf + 98304;    // 16384
    unsigned short* P    = wbf + 114688;   // 32768*256 bf16 partials (16.8MB)

    // zero bf16 accumulators + counts (8MB + 256KB)
    (void)hipMemsetAsync(d_ws, 0, (size_t)(2097152 * 2 * 2 + 32768 * 2 * 4), stream);

    prep_weights<<<448, 256, 0, stream>>>(We1, We2, Wn1, Wn2, wbf);

    partial_kernel<<<(NBATCH * NNODES) / 64, 256, 0, stream>>>(V, wp, P);

    edge_kernel<<<(NBATCH * NEDGES) / TE, 512, 0, stream>>>(
        E, edges, P, w1ef, be1, w2f, us_m0, us_m1, c0, c1);

    node_kernel<<<(NBATCH * NNODES) / 64, 256, 0, stream>>>(
        V, us_m0, us_m1, c0, c1, be2, wn1t, bn1, wn2t, bn2, node_emb);

    attn_kernel<<<(NBATCH * NNODES) / 4, 256, 0, stream>>>(
        blocks, node_emb, w_attn, rms_w, out);
}

// Round 12
// 361.214 us; speedup vs baseline: 1.4002x; 1.0101x over previous
//
#include <hip/hip_runtime.h>
#include <hip/hip_bf16.h>

#define D 128
#define NNODES 16384
#define NEDGES 262144
#define NBATCH 2
#define TE 128

typedef __attribute__((ext_vector_type(8))) short bf16x8;
typedef __attribute__((ext_vector_type(4))) float f32x4;

// single hardware instruction: packs 2 f32 -> 2 bf16 (RNE)
__device__ __forceinline__ unsigned int pk2bf(float lo, float hi) {
    unsigned int r;
    asm("v_cvt_pk_bf16_f32 %0, %1, %2" : "=v"(r) : "v"(lo), "v"(hi));
    return r;
}

__device__ __forceinline__ unsigned short f2bf(float f) {
    return (unsigned short)pk2bf(f, f);
}

__device__ __forceinline__ float bflo(unsigned int u) {
    return __uint_as_float(u << 16);
}
__device__ __forceinline__ float bfhi(unsigned int u) {
    return __uint_as_float(u & 0xffff0000u);
}

__device__ __forceinline__ bf16x8 pack8(f32x4 a, f32x4 b) {
    typedef __attribute__((ext_vector_type(4))) unsigned int u32x4;
    u32x4 u;
    u.x = pk2bf(a[0], a[1]);
    u.y = pk2bf(a[2], a[3]);
    u.z = pk2bf(b[0], b[1]);
    u.w = pk2bf(b[2], b[3]);
    return __builtin_bit_cast(bf16x8, u);
}

// memory-side packed bf16 atomic add (2 cols per dword-RMW)
__device__ __forceinline__ void atomic_pk(unsigned int* p, unsigned int v) {
    asm volatile("global_atomic_pk_add_bf16 %0, %1, off" :: "v"(p), "v"(v) : "memory");
}

// --------------------------------------------------------------- weight prep
// wbf layout (ushort offsets):
//   w1ef @ 0     : We1 E-part (rows 256..383) in MFMA B-frag order, ks<4
//   w2f  @ 16384 : We2 frag order, ks<4
//   wp   @ 32768 : [W1s|W1r] as [j][k]: wp[j*128+k] = We1[(j<128?k:128+k)][j&127]
//   wn1t @ 65536 : Wn1^T [n][k] k<256
//   wn2t @ 98304 : Wn2^T [n][k] k<128
__global__ __launch_bounds__(256)
void prep_weights(const float* __restrict__ We1, const float* __restrict__ We2,
                  const float* __restrict__ Wn1, const float* __restrict__ Wn2,
                  unsigned short* __restrict__ w)
{
    int id = blockIdx.x * 256 + threadIdx.x;   // 114688 total
    if (id < 16384) {
        int e = id & 7, l = (id >> 3) & 63, nblk = (id >> 9) & 7, ks = id >> 12;
        int k = 256 + ks * 32 + ((l >> 4) & 3) * 8 + e;
        int col = nblk * 16 + (l & 15);
        w[id] = f2bf(We1[k * 128 + col]);
    } else if (id < 32768) {
        int i2 = id - 16384;
        int e = i2 & 7, l = (i2 >> 3) & 63, nblk = (i2 >> 9) & 7, ks = i2 >> 12;
        int k = ks * 32 + ((l >> 4) & 3) * 8 + e;
        int col = nblk * 16 + (l & 15);
        w[id] = f2bf(We2[k * 128 + col]);
    } else if (id < 65536) {
        int i3 = id - 32768;
        int j = i3 >> 7, k = i3 & 127;
        int row = (j < 128) ? k : (128 + k);
        w[id] = f2bf(We1[row * 128 + (j & 127)]);
    } else if (id < 98304) {
        int i4 = id - 65536;
        int n = i4 >> 8, k = i4 & 255;
        w[id] = f2bf(Wn1[k * 128 + n]);
    } else {
        int i5 = id - 98304;
        int n = i5 >> 7, k = i5 & 127;
        w[id] = f2bf(Wn2[k * 128 + n]);
    }
}

// ------------------------------------------------------------ partial kernel
// P2[r][pcol]: PERMUTED layout so the 4 cols a lane needs are adjacent:
//   original col = part*128 + sub*64 + n*16 + l15  (part: 0=snd,1=rcv)
//   stored at      part*128 + sub*64 + l15*4 + n
__global__ __launch_bounds__(256)
void partial_kernel(const float* __restrict__ V, const unsigned short* __restrict__ wp,
                    unsigned short* __restrict__ P)
{
    __shared__ unsigned short smem[64 * 136];
    const int t = threadIdx.x, lane = t & 63, wave = t >> 6;
    const int l15 = lane & 15, l4 = lane >> 4;
    const long long r0 = (long long)blockIdx.x * 64;

    for (int i = t; i < 64 * 32; i += 256) {
        int c4 = i & 31, r = i >> 5;
        float4 v = *(const float4*)(V + (r0 + r) * 128 + c4 * 4);
        uint2 p; p.x = pk2bf(v.x, v.y); p.y = pk2bf(v.z, v.w);
        *(uint2*)(&smem[r * 136 + c4 * 4]) = p;
    }
    __syncthreads();

    const int j0 = wave * 64;
    f32x4 acc[4][4] = {};
    const unsigned short* bb0 = wp + (j0 + l15) * 128 + l4 * 8;
    #pragma unroll
    for (int ks = 0; ks < 4; ++ks) {
        bf16x8 bb[4];
        #pragma unroll
        for (int n = 0; n < 4; ++n)
            bb[n] = *(const bf16x8*)(bb0 + n * 16 * 128 + ks * 32);
        #pragma unroll
        for (int mq = 0; mq < 4; ++mq) {
            bf16x8 a = *(const bf16x8*)(&smem[(mq * 16 + l15) * 136 + l4 * 8 + ks * 32]);
            #pragma unroll
            for (int n = 0; n < 4; ++n)
                acc[mq][n] = __builtin_amdgcn_mfma_f32_16x16x32_bf16(a, bb[n], acc[mq][n], 0, 0, 0);
        }
    }
    // permuted store: 4 n-adjacent cols -> 2 uint writes
    const int pbase = (wave >> 1) * 128 + (wave & 1) * 64 + l15 * 4;
    #pragma unroll
    for (int mq = 0; mq < 4; ++mq) {
        #pragma unroll
        for (int i = 0; i < 4; ++i) {
            int row = mq * 16 + l4 * 4 + i;
            uint2 pw;
            pw.x = pk2bf(acc[mq][0][i], acc[mq][1][i]);
            pw.y = pk2bf(acc[mq][2][i], acc[mq][3][i]);
            *(uint2*)(P + (r0 + row) * 256 + pbase) = pw;
        }
    }
}

// ---------------------------------------------------------------- edge kernel
// 128 edges/block, 8 waves, 512 threads. P-gather issued BEFORE the layer-1
// MFMA loop (only depends on edge indices) so L3 gather latency hides under
// MFMA1 + cvt. All f32->bf16 via v_cvt_pk_bf16_f32. Single barrier.
__global__ __launch_bounds__(512)
void edge_kernel(const float* __restrict__ E, const int* __restrict__ edges,
                 const unsigned short* __restrict__ P,
                 const unsigned short* __restrict__ w1ef, const float* __restrict__ be1,
                 const unsigned short* __restrict__ w2f,
                 unsigned short* __restrict__ us_m0, unsigned short* __restrict__ us_m1,
                 float* __restrict__ c0, float* __restrict__ c1)
{
    __shared__ unsigned short Hbuf[TE * 136];

    const int t    = threadIdx.x;
    const int lane = t & 63;
    const int wave = t >> 6;
    const int wr   = wave >> 1;          // 0..3 (32-edge row block)
    const int wc   = wave & 1;           // 0..1 (64-col block)
    const int l15  = lane & 15;
    const int l4   = lane >> 4;

    const long long eflat0 = (long long)blockIdx.x * TE;
    const int b  = (int)(eflat0 / NEDGES);
    const long long nb0 = (long long)b * NNODES;

    // degree counts
    if (t < TE) {
        int2 e2 = *(const int2*)(edges + (eflat0 + t) * 2);
        atomicAdd(&c0[nb0 + e2.x], 1.f);
        atomicAdd(&c1[nb0 + e2.y], 1.f);
    }

    // ---- node indices first (needed by the P gather) ----
    int nd0[2][4], nd1[2][4];
    #pragma unroll
    for (int m = 0; m < 2; ++m) {
        #pragma unroll
        for (int i = 0; i < 4; ++i) {
            int row = wr * 32 + m * 16 + l4 * 4 + i;
            int2 e2 = *(const int2*)(edges + (eflat0 + row) * 2);
            nd0[m][i] = e2.x;
            nd1[m][i] = e2.y;
        }
    }

    // ---- P gather issued EARLY: latency hides under MFMA1 below ----
    const unsigned short* Pb = P + nb0 * 256;
    const unsigned int wcl = wc * 64 + l15 * 4;
    uint2 su[2][4], ru[2][4];
    #pragma unroll
    for (int m = 0; m < 2; ++m) {
        #pragma unroll
        for (int i = 0; i < 4; ++i) {
            su[m][i] = *(const uint2*)(Pb + (unsigned)nd0[m][i] * 256u + wcl);
            ru[m][i] = *(const uint2*)(Pb + (unsigned)nd1[m][i] * 256u + 128u + wcl);
        }
    }

    // ---- layer 1 (E part): [128x128] @ [128x128], A direct from global ----
    f32x4 acc[2][4] = {};
    {
        const float* er0 = E + (eflat0 + wr * 32 + l15) * D + l4 * 8;
        #pragma unroll
        for (int ks = 0; ks < 4; ++ks) {
            f32x4 xa0 = *(const f32x4*)(er0 + ks * 32);
            f32x4 xb0 = *(const f32x4*)(er0 + ks * 32 + 4);
            f32x4 xa1 = *(const f32x4*)(er0 + 16 * D + ks * 32);
            f32x4 xb1 = *(const f32x4*)(er0 + 16 * D + ks * 32 + 4);
            bf16x8 a0 = pack8(xa0, xb0);
            bf16x8 a1 = pack8(xa1, xb1);
            #pragma unroll
            for (int n = 0; n < 4; ++n) {
                bf16x8 bb = *(const bf16x8*)(w1ef + (((ks * 8 + wc * 4 + n) * 64 + lane) << 3));
                acc[0][n] = __builtin_amdgcn_mfma_f32_16x16x32_bf16(a0, bb, acc[0][n], 0, 0, 0);
                acc[1][n] = __builtin_amdgcn_mfma_f32_16x16x32_bf16(a1, bb, acc[1][n], 0, 0, 0);
            }
        }
    }

    // epilogue: + P_s + P_r + bias, silu -> Hbuf
    float bia[4];
    #pragma unroll
    for (int n = 0; n < 4; ++n) bia[n] = be1[wc * 64 + n * 16 + l15];
    #pragma unroll
    for (int m = 0; m < 2; ++m) {
        #pragma unroll
        for (int i = 0; i < 4; ++i) {
            int row = wr * 32 + m * 16 + l4 * 4 + i;
            float ps[4] = { bflo(su[m][i].x), bfhi(su[m][i].x),
                            bflo(su[m][i].y), bfhi(su[m][i].y) };
            float pr[4] = { bflo(ru[m][i].x), bfhi(ru[m][i].x),
                            bflo(ru[m][i].y), bfhi(ru[m][i].y) };
            #pragma unroll
            for (int n = 0; n < 4; ++n) {
                float a = acc[m][n][i] + bia[n] + ps[n] + pr[n];
                Hbuf[row * 136 + wc * 64 + n * 16 + l15] = f2bf(a / (1.f + __expf(-a)));
            }
        }
    }
    __syncthreads();   // single barrier: H handoff

    // ---- layer 2: [128x128] @ [128x128] ----
    f32x4 acc2[2][4] = {};
    {
        const unsigned short* hrow = &Hbuf[(wr * 32 + l15) * 136 + l4 * 8];
        #pragma unroll
        for (int ks = 0; ks < 4; ++ks) {
            bf16x8 a0 = *(const bf16x8*)(hrow + ks * 32);
            bf16x8 a1 = *(const bf16x8*)(hrow + 16 * 136 + ks * 32);
            #pragma unroll
            for (int n = 0; n < 4; ++n) {
                bf16x8 bb = *(const bf16x8*)(w2f + (((ks * 8 + wc * 4 + n) * 64 + lane) << 3));
                acc2[0][n] = __builtin_amdgcn_mfma_f32_16x16x32_bf16(a0, bb, acc2[0][n], 0, 0, 0);
                acc2[1][n] = __builtin_amdgcn_mfma_f32_16x16x32_bf16(a1, bb, acc2[1][n], 0, 0, 0);
            }
        }
    }

    // scatter: packed bf16 atomics (xor-1 lane pairs, even lane issues)
    {
        unsigned short* dst_arr = wc ? us_m1 : us_m0;
        #pragma unroll
        for (int n = 0; n < 4; ++n) {
            int colh = n * 16 + l15;
            #pragma unroll
            for (int m = 0; m < 2; ++m) {
                #pragma unroll
                for (int i = 0; i < 4; ++i) {
                    int node = wc ? nd1[m][i] : nd0[m][i];
                    float v  = acc2[m][n][i];
                    float vn = __shfl_xor(v, 1);
                    if (!(lane & 1)) {
                        atomic_pk((unsigned int*)(dst_arr + (nb0 + node) * 64 + colh),
                                  pk2bf(v, vn));
                    }
                }
            }
        }
    }
}

// ---------------------------------------------------------------- node kernel
// m0/m1 bf16 sums; divide by count and add be2 (count-gated) at staging.
__global__ __launch_bounds__(256)
void node_kernel(const float* __restrict__ V,
                 const unsigned short* __restrict__ m0, const unsigned short* __restrict__ m1,
                 const float* __restrict__ c0, const float* __restrict__ c1,
                 const float* __restrict__ be2,
                 const unsigned short* __restrict__ wn1t, const float* __restrict__ bn1,
                 const unsigned short* __restrict__ wn2t, const float* __restrict__ bn2,
                 float* __restrict__ node_emb)
{
    __shared__ unsigned short smem[64 * 264];   // A [64][264]; reused as H [64][136]

    const int t    = threadIdx.x;
    const int lane = t & 63;
    const int wave = t >> 6;
    const int wr   = wave >> 1;
    const int wc   = wave & 1;
    const int l15  = lane & 15;
    const int l4   = lane >> 4;

    const long long nflat0 = (long long)blockIdx.x * 64;

    for (int i = t; i < 64 * 48; i += 256) {
        int n  = i / 48;
        int c4 = i - n * 48;
        long long node = nflat0 + n;
        if (c4 < 32) {
            float4 v = *(const float4*)(V + node * 128 + c4 * 4);
            uint2 p; p.x = pk2bf(v.x, v.y); p.y = pk2bf(v.z, v.w);
            *(uint2*)(&smem[n * 264 + c4 * 4]) = p;
        } else {
            int dir = (c4 >= 40);
            int j = c4 - 32 - dir * 8;
            const unsigned short* src = dir ? m1 : m0;
            float cnt = (dir ? c1 : c0)[node];
            float inv = 1.f / fmaxf(cnt, 1.f);
            float bon = (cnt >= 1.f) ? 1.f : 0.f;     // zero-degree: mean=0, no bias
            uint4 raw = *(const uint4*)(src + node * 64 + j * 8);
            const float* bb = be2 + dir * 64 + j * 8;
            unsigned int rr[4] = {raw.x, raw.y, raw.z, raw.w};
            unsigned int o[4];
            #pragma unroll
            for (int q = 0; q < 4; ++q) {
                float lo = bflo(rr[q]) * inv + bb[2 * q] * bon;
                float hi = bfhi(rr[q]) * inv + bb[2 * q + 1] * bon;
                o[q] = pk2bf(lo, hi);
            }
            uint4 st; st.x = o[0]; st.y = o[1]; st.z = o[2]; st.w = o[3];
            *(uint4*)(&smem[n * 264 + 128 + dir * 64 + j * 8]) = st;
        }
    }
    __syncthreads();

    f32x4 acc[2][4] = {};
    {
        const unsigned short* arow = &smem[(wr * 32 + l15) * 264 + l4 * 8];
        const unsigned short* bb0  = wn1t + (wc * 64 + l15) * 256 + l4 * 8;
        for (int ks = 0; ks < 8; ++ks) {
            bf16x8 a0 = *(const bf16x8*)(arow + ks * 32);
            bf16x8 a1 = *(const bf16x8*)(arow + 16 * 264 + ks * 32);
            #pragma unroll
            for (int n = 0; n < 4; ++n) {
                bf16x8 bb = *(const bf16x8*)(bb0 + n * 16 * 256 + ks * 32);
                acc[0][n] = __builtin_amdgcn_mfma_f32_16x16x32_bf16(a0, bb, acc[0][n], 0, 0, 0);
                acc[1][n] = __builtin_amdgcn_mfma_f32_16x16x32_bf16(a1, bb, acc[1][n], 0, 0, 0);
            }
        }
    }
    __syncthreads();

    #pragma unroll
    for (int n = 0; n < 4; ++n) {
        int col = wc * 64 + n * 16 + l15;
        float bias = bn1[col];
        #pragma unroll
        for (int m = 0; m < 2; ++m) {
            #pragma unroll
            for (int i = 0; i < 4; ++i) {
                int row = wr * 32 + m * 16 + l4 * 4 + i;
                float a = acc[m][n][i] + bias;
                smem[row * 136 + col] = f2bf(a / (1.f + __expf(-a)));
            }
        }
    }
    __syncthreads();

    f32x4 acc2[2][4] = {};
    {
        const unsigned short* hrow = &smem[(wr * 32 + l15) * 136 + l4 * 8];
        const unsigned short* bb0  = wn2t + (wc * 64 + l15) * 128 + l4 * 8;
        #pragma unroll
        for (int ks = 0; ks < 4; ++ks) {
            bf16x8 a0 = *(const bf16x8*)(hrow + ks * 32);
            bf16x8 a1 = *(const bf16x8*)(hrow + 16 * 136 + ks * 32);
            #pragma unroll
            for (int n = 0; n < 4; ++n) {
                bf16x8 bb = *(const bf16x8*)(bb0 + n * 16 * 128 + ks * 32);
                acc2[0][n] = __builtin_amdgcn_mfma_f32_16x16x32_bf16(a0, bb, acc2[0][n], 0, 0, 0);
                acc2[1][n] = __builtin_amdgcn_mfma_f32_16x16x32_bf16(a1, bb, acc2[1][n], 0, 0, 0);
            }
        }
    }

    #pragma unroll
    for (int n = 0; n < 4; ++n) {
        int col = wc * 64 + n * 16 + l15;
        float bias = bn2[col];
        #pragma unroll
        for (int m = 0; m < 2; ++m) {
            #pragma unroll
            for (int i = 0; i < 4; ++i) {
                long long row = nflat0 + wr * 32 + m * 16 + l4 * 4 + i;
                node_emb[row * 128 + col] = acc2[m][n][i] + bias;
            }
        }
    }
}

// ------------------------------------------------------------ attention kernel
__global__ __launch_bounds__(256)
void attn_kernel(const float* __restrict__ blocks, const float* __restrict__ node_emb,
                 const float* __restrict__ w_attn, const float* __restrict__ rms_w,
                 float* __restrict__ out)
{
    const int t    = threadIdx.x;
    const int wave = t >> 6;
    const int lane = t & 63;
    const long long node = (long long)blockIdx.x * 4 + wave;
    const int d0 = lane * 2;

    float2 wa = *(const float2*)(w_attn + d0);
    float2 rw = *(const float2*)(rms_w + d0);

    float xs[5][2];
    float lg[5];
    #pragma unroll
    for (int s = 0; s < 5; ++s) {
        const float* src = (s < 4)
            ? (blocks + ((long long)s * NBATCH * NNODES + node) * 128)
            : (node_emb + node * 128);
        float2 x = *(const float2*)(src + d0);
        xs[s][0] = x.x; xs[s][1] = x.y;
        float ss = x.x * x.x + x.y * x.y;
        float wv = wa.x * rw.x * x.x + wa.y * rw.y * x.y;
        #pragma unroll
        for (int m = 1; m < 64; m <<= 1) {
            ss += __shfl_xor(ss, m);
            wv += __shfl_xor(wv, m);
        }
        lg[s] = wv * rsqrtf(ss * (1.f / 128.f) + 1e-6f);
    }

    float mx = lg[0];
    #pragma unroll
    for (int s = 1; s < 5; ++s) mx = fmaxf(mx, lg[s]);
    float ex[5], sum = 0.f;
    #pragma unroll
    for (int s = 0; s < 5; ++s) { ex[s] = __expf(lg[s] - mx); sum += ex[s]; }
    float inv = 1.f / sum;

    float h0 = 0.f, h1 = 0.f;
    #pragma unroll
    for (int s = 0; s < 5; ++s) {
        float a = ex[s] * inv;
        h0 = fmaf(a, xs[s][0], h0);
        h1 = fmaf(a, xs[s][1], h1);
    }
    *(float2*)(out + node * 128 + d0) = make_float2(h0, h1);
}

// ------------------------------------------------------------------- launcher
extern "C" void kernel_launch(void* const* d_in, const int* in_sizes, int n_in,
                              void* d_out, int out_size, void* d_ws, size_t ws_size,
                              hipStream_t stream)
{
    const float* V      = (const float*)d_in[0];
    const float* E      = (const float*)d_in[1];
    const float* blocks = (const float*)d_in[2];
    const float* We1    = (const float*)d_in[3];
    const float* be1    = (const float*)d_in[4];
    const float* We2    = (const float*)d_in[5];
    const float* be2    = (const float*)d_in[6];
    const float* Wn1    = (const float*)d_in[7];
    const float* bn1    = (const float*)d_in[8];
    const float* Wn2    = (const float*)d_in[9];
    const float* bn2    = (const float*)d_in[10];
    const float* w_attn = (const float*)d_in[11];
    const float* rms_w  = (const float*)d_in[12];
    const int*   edges  = (const int*)d_in[13];
    float* out = (float*)d_out;

    // ws layout: [us_m0 bf16 4MB][us_m1 bf16 4MB][c0 128KB][c1 128KB]
    //            [node_emb f32 16MB][wbf 224KB][P bf16 16.8MB]
    unsigned short* us_m0 = (unsigned short*)d_ws;          // 2097152 ushort
    unsigned short* us_m1 = us_m0 + 2097152;
    float* c0       = (float*)(us_m1 + 2097152);
    float* c1       = c0 + 32768;
    float* node_emb = c1 + 32768;
    unsigned short* wbf = (unsigned short*)(node_emb + 4194304);  // 114688 bf16
    unsigned short* w1ef = wbf;            // 16384 (frag-ordered We1 E-part)
    unsigned short* w2f  = wbf + 16384;    // 16384 (frag-ordered We2)
    unsigned short* wp   = wbf + 32768;    // 32768 ([W1s|W1r] transposed)
    unsigned short* wn1t = wbf + 65536;    // 32768
    unsigned short* wn2t = wbf + 98304;    // 16384
    unsigned short* P    = wbf + 114688;   // 32768*256 bf16 partials (16.8MB)

    // zero bf16 accumulators + counts (8MB + 256KB)
    (void)hipMemsetAsync(d_ws, 0, (size_t)(2097152 * 2 * 2 + 32768 * 2 * 4), stream);

    prep_weights<<<448, 256, 0, stream>>>(We1, We2, Wn1, Wn2, wbf);

    partial_kernel<<<(NBATCH * NNODES) / 64, 256, 0, stream>>>(V, wp, P);

    edge_kernel<<<(NBATCH * NEDGES) / TE, 512, 0, stream>>>(
        E, edges, P, w1ef, be1, w2f, us_m0, us_m1, c0, c1);

    node_kernel<<<(NBATCH * NNODES) / 64, 256, 0, stream>>>(
        V, us_m0, us_m1, c0, c1, be2, wn1t, bn1, wn2t, bn2, node_emb);

    attn_kernel<<<(NBATCH * NNODES) / 4, 256, 0, stream>>>(
        blocks, node_emb, w_attn, rms_w, out);
}